// Round 7
// baseline (488.145 us; speedup 1.0000x reference)
//
#include <hip/hip_runtime.h>

#define DIM    512
#define NCLS   128
#define NCENT  8
#define TM     64
#define KC     32
#define WSLOT  64      // padded neighbor-slot width (max degree guard)
#define MARGIN 0.05f   // > worst-case bf16-induced router-score error (~0.033)

typedef unsigned short ushort_t;
typedef unsigned int   uint_t;

static __device__ __forceinline__ ushort_t f2bf(float f) {
    uint_t x = __float_as_uint(f);
    uint_t r = (x + 0x7fffu + ((x >> 16) & 1u)) >> 16;   // RTNE (finite inputs)
    return (ushort_t)r;
}
static __device__ __forceinline__ float bf_lo(uint_t w) {
    return __uint_as_float(w << 16);
}
static __device__ __forceinline__ float bf_hi(uint_t w) {
    return __uint_as_float(w & 0xffff0000u);
}

// --- prep: hb = bf16(h); q = h @ Ws^T (f32, router-exact). Wave/node. --------

__global__ __launch_bounds__(256) void prep_kernel(const float* __restrict__ h,
                                                   const float* __restrict__ Ws,
                                                   ushort_t* __restrict__ hb,
                                                   float* __restrict__ q, int N) {
    int wid = (blockIdx.x * 256 + threadIdx.x) >> 6;   // node
    int lane = threadIdx.x & 63;
    if (wid >= N) return;                               // wave-uniform exit

    const float* row = h + (size_t)wid * DIM + lane * 8;
    float4 a = *(const float4*)row;
    float4 b = *(const float4*)(row + 4);
    float fa[8] = {a.x, a.y, a.z, a.w, b.x, b.y, b.z, b.w};

    union { ushort_t us[8]; uint4 v; } pk;
    #pragma unroll
    for (int i = 0; i < 8; ++i) pk.us[i] = f2bf(fa[i]);
    *(uint4*)(hb + (size_t)wid * DIM + lane * 8) = pk.v;

    float qv = 0.f;
    #pragma unroll
    for (int c = 0; c < NCENT; ++c) {
        const float* w = Ws + c * DIM + lane * 8;
        float4 w0 = *(const float4*)w;
        float4 w1 = *(const float4*)(w + 4);
        float p = fa[0]*w0.x + fa[1]*w0.y + fa[2]*w0.z + fa[3]*w0.w
                + fa[4]*w1.x + fa[5]*w1.y + fa[6]*w1.z + fa[7]*w1.w;
        #pragma unroll
        for (int s = 32; s > 0; s >>= 1) p += __shfl_xor(p, s, 64);
        if (lane == c) qv = p;
    }
    if (lane < NCENT) q[(size_t)wid * NCENT + lane] = qv;
}

// --- padded-slot CSR: one atomic pass ----------------------------------------

__global__ __launch_bounds__(256) void scatter_pad_kernel(const int* __restrict__ src,
                                                          const int* __restrict__ dst,
                                                          int* __restrict__ cnt,
                                                          int* __restrict__ slots, int E) {
    int i = blockIdx.x * 256 + threadIdx.x;
    if (i < E) {
        int d = dst[i];
        int k = atomicAdd(&cnt[d], 1);
        if (k < WSLOT) slots[(size_t)d * WSLOT + k] = src[i];
    }
}

// --- gather-mean (bf16, 4 waves/node) + margin router ------------------------

__global__ __launch_bounds__(256) void gather_hb_kernel(
        const ushort_t* __restrict__ hb, const int* __restrict__ cnt,
        const int* __restrict__ slots, const float* __restrict__ Ws,
        float* __restrict__ hm, int* __restrict__ route,
        int* __restrict__ gcnt, int* __restrict__ nsus,
        int* __restrict__ suslist, int N) {
    int node = blockIdx.x;
    int tid = threadIdx.x;
    int wv = tid >> 6;        // 0..3
    int lane = tid & 63;

    __shared__ float part[4][DIM];     // 8 KB partial sums
    __shared__ float scred[4][NCENT];

    int cn = cnt[node]; if (cn > WSLOT) cn = WSLOT;
    const int* sl = slots + (size_t)node * WSLOT;
    // wave wv owns slots j = wv + 4*l, l < mcount  (mcount <= 16)
    int mcount = (cn > wv) ? ((cn - wv + 3) >> 2) : 0;
    int myslot = (lane < mcount) ? sl[wv + 4 * lane] : 0;

    float acc[8];
    if (wv == 0) {   // self loop (exactly once)
        uint4 u = *(const uint4*)(hb + (size_t)node * DIM + lane * 8);
        acc[0] = bf_lo(u.x); acc[1] = bf_hi(u.x);
        acc[2] = bf_lo(u.y); acc[3] = bf_hi(u.y);
        acc[4] = bf_lo(u.z); acc[5] = bf_hi(u.z);
        acc[6] = bf_lo(u.w); acc[7] = bf_hi(u.w);
    } else {
        #pragma unroll
        for (int k = 0; k < 8; ++k) acc[k] = 0.f;
    }

    int j = 0;
    for (; j + 8 <= mcount; j += 8) {
        uint4 u[8];
        #pragma unroll
        for (int k = 0; k < 8; ++k) {
            int s = __shfl(myslot, j + k, 64);
            u[k] = *(const uint4*)(hb + (size_t)s * DIM + lane * 8);
        }
        #pragma unroll
        for (int k = 0; k < 8; ++k) {
            acc[0] += bf_lo(u[k].x); acc[1] += bf_hi(u[k].x);
            acc[2] += bf_lo(u[k].y); acc[3] += bf_hi(u[k].y);
            acc[4] += bf_lo(u[k].z); acc[5] += bf_hi(u[k].z);
            acc[6] += bf_lo(u[k].w); acc[7] += bf_hi(u[k].w);
        }
    }
    for (; j < mcount; ++j) {
        int s = __shfl(myslot, j, 64);
        uint4 u = *(const uint4*)(hb + (size_t)s * DIM + lane * 8);
        acc[0] += bf_lo(u.x); acc[1] += bf_hi(u.x);
        acc[2] += bf_lo(u.y); acc[3] += bf_hi(u.y);
        acc[4] += bf_lo(u.z); acc[5] += bf_hi(u.z);
        acc[6] += bf_lo(u.w); acc[7] += bf_hi(u.w);
    }

    float4 p0 = {acc[0], acc[1], acc[2], acc[3]};
    float4 p1 = {acc[4], acc[5], acc[6], acc[7]};
    *(float4*)&part[wv][lane * 8]     = p0;
    *(float4*)&part[wv][lane * 8 + 4] = p1;
    __syncthreads();

    // combine partials; thread t owns dims 2t, 2t+1
    int d = tid * 2;
    float inv = 1.0f / (float)(cn + 1);
    float v0 = (part[0][d]     + part[1][d])     + (part[2][d]     + part[3][d]);
    float v1 = (part[0][d + 1] + part[1][d + 1]) + (part[2][d + 1] + part[3][d + 1]);
    v0 *= inv; v1 *= inv;
    *(float2*)(hm + (size_t)node * DIM + d) = make_float2(v0, v1);

    // router partial scores from the reduced mean (no extra memory requests)
    float sc[NCENT];
    #pragma unroll
    for (int c = 0; c < NCENT; ++c) {
        float2 w = *(const float2*)(Ws + c * DIM + d);
        sc[c] = v0 * w.x + v1 * w.y;
    }
    #pragma unroll
    for (int c = 0; c < NCENT; ++c) {
        float v = sc[c];
        #pragma unroll
        for (int s = 32; s > 0; s >>= 1) v += __shfl_xor(v, s, 64);
        sc[c] = v;
    }
    if (lane == 0) {
        #pragma unroll
        for (int c = 0; c < NCENT; ++c) scred[wv][c] = sc[c];
    }
    __syncthreads();
    if (tid == 0) {
        float s[NCENT];
        #pragma unroll
        for (int c = 0; c < NCENT; ++c)
            s[c] = (scred[0][c] + scred[1][c]) + (scred[2][c] + scred[3][c]);
        int bi = 0; float bv = s[0];
        #pragma unroll
        for (int c = 1; c < NCENT; ++c)
            if (s[c] > bv) { bv = s[c]; bi = c; }      // strict > = first max
        float sec = -1e30f;
        #pragma unroll
        for (int c = 0; c < NCENT; ++c)
            if (c != bi) sec = fmaxf(sec, s[c]);
        route[node] = bi;
        if (bv - sec < MARGIN) {                        // too close: exact recheck
            int k = atomicAdd(nsus, 1);
            suslist[k] = node;
        } else {
            atomicAdd(&gcnt[bi], 1);
        }
    }
}

// --- fixup: exact f32 q-sum route for margin suspects. One wave/suspect. -----

__global__ __launch_bounds__(256) void fixup_kernel(
        const float* __restrict__ q, const int* __restrict__ cnt,
        const int* __restrict__ slots, const int* __restrict__ suslist,
        const int* __restrict__ nsus, int* __restrict__ route,
        int* __restrict__ gcnt, int N) {
    int w = (blockIdx.x * 256 + threadIdx.x) >> 6;
    int lane = threadIdx.x & 63;
    int ns = *nsus;
    if (w >= ns) return;                                // wave-uniform
    int node = suslist[w];
    int cn = cnt[node]; if (cn > WSLOT) cn = WSLOT;

    float qs[NCENT];
    if (lane < cn) {
        int s = slots[(size_t)node * WSLOT + lane];
        const float* qr = q + (size_t)s * NCENT;
        float4 q0 = *(const float4*)qr;
        float4 q1 = *(const float4*)(qr + 4);
        qs[0]=q0.x; qs[1]=q0.y; qs[2]=q0.z; qs[3]=q0.w;
        qs[4]=q1.x; qs[5]=q1.y; qs[6]=q1.z; qs[7]=q1.w;
    } else {
        #pragma unroll
        for (int c = 0; c < NCENT; ++c) qs[c] = 0.f;
    }
    #pragma unroll
    for (int c = 0; c < NCENT; ++c) {
        float v = qs[c];
        #pragma unroll
        for (int s = 32; s > 0; s >>= 1) v += __shfl_xor(v, s, 64);
        qs[c] = v;
    }
    if (lane == 0) {
        const float* qn = q + (size_t)node * NCENT;     // self-loop row
        int best = 0; float bv = qs[0] + qn[0];
        #pragma unroll
        for (int c = 1; c < NCENT; ++c) {
            float v = qs[c] + qn[c];
            if (v > bv) { bv = v; best = c; }           // strict > = first max
        }
        route[node] = best;
        atomicAdd(&gcnt[best], 1);
    }
}

// --- group nodes by route ----------------------------------------------------

__global__ void group_prep_kernel(const int* __restrict__ gcnt,
                                  int* __restrict__ goff, int* __restrict__ gcur,
                                  int* __restrict__ tloff) {
    if (threadIdx.x == 0 && blockIdx.x == 0) {
        int g = 0, tt = 0;
        for (int c = 0; c < NCENT; ++c) {
            goff[c] = g; gcur[c] = g; tloff[c] = tt;
            g += gcnt[c]; tt += (gcnt[c] + TM - 1) / TM;
        }
        goff[NCENT] = g; tloff[NCENT] = tt;
    }
}

__global__ __launch_bounds__(256) void group_scatter_kernel(
        const int* __restrict__ route, int* __restrict__ gcur,
        int* __restrict__ nlist, int N) {
    int i = blockIdx.x * 256 + threadIdx.x;
    if (i < N) {
        int r = route[i];
        int p = atomicAdd(&gcur[r], 1);
        nlist[p] = i;
    }
}

// --- grouped GEMM  out[n, :] = hm[n, :] @ Wt[route(n)]^T ---------------------

__global__ __launch_bounds__(256) void gemm_kernel(
        const float* __restrict__ hm, const int* __restrict__ nlist,
        const int* __restrict__ goff, const int* __restrict__ tloff,
        const float* __restrict__ Wt, float* __restrict__ out) {
    __shared__ float a_s[TM][KC + 1];
    __shared__ float b_s[NCLS][KC + 1];

    int b = blockIdx.x;
    if (b >= tloff[NCENT]) return;
    int c = 0;
    while (b >= tloff[c + 1]) ++c;
    int row0 = goff[c] + (b - tloff[c]) * TM;
    int mrows = goff[c + 1] - row0; if (mrows > TM) mrows = TM;

    int tid = threadIdx.x;
    int tn = tid & 31;
    int tm = tid >> 5;

    float acc[8][4];
    #pragma unroll
    for (int i = 0; i < 8; ++i)
        #pragma unroll
        for (int j = 0; j < 4; ++j) acc[i][j] = 0.f;

    const float* wt_c = Wt + (size_t)c * NCLS * DIM;

    for (int k0 = 0; k0 < DIM; k0 += KC) {
        #pragma unroll
        for (int r = 0; r < 2; ++r) {
            int cidx = tid + 256 * r;
            int row = cidx >> 3;
            int kq = (cidx & 7) * 4;
            int rr = row < mrows ? row : mrows - 1;
            int nd = nlist[row0 + rr];
            float4 v = *(const float4*)(hm + (size_t)nd * DIM + k0 + kq);
            a_s[row][kq] = v.x; a_s[row][kq+1] = v.y;
            a_s[row][kq+2] = v.z; a_s[row][kq+3] = v.w;
        }
        #pragma unroll
        for (int r = 0; r < 4; ++r) {
            int cidx = tid + 256 * r;
            int row = cidx >> 3;
            int kq = (cidx & 7) * 4;
            float4 v = *(const float4*)(wt_c + (size_t)row * DIM + k0 + kq);
            b_s[row][kq] = v.x; b_s[row][kq+1] = v.y;
            b_s[row][kq+2] = v.z; b_s[row][kq+3] = v.w;
        }
        __syncthreads();
        #pragma unroll
        for (int k = 0; k < KC; ++k) {
            float bv[4];
            #pragma unroll
            for (int j = 0; j < 4; ++j) bv[j] = b_s[tn + 32 * j][k];
            #pragma unroll
            for (int i = 0; i < 8; ++i) {
                float av = a_s[tm * 8 + i][k];
                #pragma unroll
                for (int j = 0; j < 4; ++j) acc[i][j] += av * bv[j];
            }
        }
        __syncthreads();
    }

    #pragma unroll
    for (int i = 0; i < 8; ++i) {
        int row = tm * 8 + i;
        if (row < mrows) {
            int nd = nlist[row0 + row];
            #pragma unroll
            for (int j = 0; j < 4; ++j)
                out[(size_t)nd * NCLS + tn + 32 * j] = acc[i][j];
        }
    }
}

// --- Fallback: fused slots-based per-node kernel (f32 end-to-end) ------------

__global__ __launch_bounds__(256) void node_kernel(const float* __restrict__ h,
                                                   const int* __restrict__ cnt,
                                                   const int* __restrict__ slots,
                                                   const float* __restrict__ Ws,
                                                   const float* __restrict__ Wt,
                                                   float* __restrict__ out) {
    int node = blockIdx.x;
    int t = threadIdx.x;
    __shared__ float hm[DIM];
    __shared__ float sc[NCENT];
    __shared__ int route_s;

    int d0 = t * 2;
    float2 acc = *(const float2*)(h + (size_t)node * DIM + d0);
    int cn = cnt[node]; if (cn > WSLOT) cn = WSLOT;
    const int* sl = slots + (size_t)node * WSLOT;
    for (int j = 0; j < cn; ++j) {
        float2 v = *(const float2*)(h + (size_t)sl[j] * DIM + d0);
        acc.x += v.x; acc.y += v.y;
    }
    float inv = 1.0f / (float)(cn + 1);
    hm[d0] = acc.x * inv; hm[d0 + 1] = acc.y * inv;
    __syncthreads();
    if (t < NCENT) {
        const float* w = Ws + t * DIM;
        float s = 0.f;
        for (int d = 0; d < DIM; d += 4) {
            float4 a = *(const float4*)(&hm[d]);
            float4 b = *(const float4*)(w + d);
            s += a.x * b.x + a.y * b.y + a.z * b.z + a.w * b.w;
        }
        sc[t] = s;
    }
    __syncthreads();
    if (t == 0) {
        int best = 0; float bv = sc[0];
        #pragma unroll
        for (int c = 1; c < NCENT; ++c)
            if (sc[c] > bv) { bv = sc[c]; best = c; }
        route_s = best;
    }
    __syncthreads();
    int route = route_s;
    if (t < NCLS) {
        const float* w = Wt + ((size_t)route * NCLS + t) * DIM;
        float s = 0.f;
        for (int d = 0; d < DIM; d += 4) {
            float4 a = *(const float4*)(&hm[d]);
            float4 b = *(const float4*)(w + d);
            s += a.x * b.x + a.y * b.y + a.z * b.z + a.w * b.w;
        }
        out[(size_t)node * NCLS + t] = s;
    }
}

// --- launch ------------------------------------------------------------------

extern "C" void kernel_launch(void* const* d_in, const int* in_sizes, int n_in,
                              void* d_out, int out_size, void* d_ws, size_t ws_size,
                              hipStream_t stream) {
    const float* h   = (const float*)d_in[0];
    const int*   ei  = (const int*)d_in[1];
    const float* Ws  = (const float*)d_in[2];
    const float* Wt  = (const float*)d_in[3];
    float*       out = (float*)d_out;

    int N = in_sizes[0] / DIM;
    int E = in_sizes[1] / 2;
    const int* esrc = ei;
    const int* edst = ei + E;

    int* wsp     = (int*)d_ws;
    int* cnt     = wsp;                      // N
    int* gcnt    = cnt + N;                  // 8
    int* nsus    = gcnt + NCENT;             // 8 (use [0])
    int* gcur    = nsus + 8;                 // 8
    int* route   = gcur + NCENT;             // N
    int* goff    = route + N;                // 9
    int* tloff   = goff + NCENT + 1;         // 9
    int* suslist = tloff + NCENT + 1;        // N
    int* nlist   = suslist + N;              // N
    int* slots   = nlist + N;                // N*WSLOT
    size_t iw    = (size_t)(4 * N) + 24 + 2 * (NCENT + 1) + (size_t)N * WSLOT;
    size_t q_off  = ((iw * 4 + 255) & ~(size_t)255);
    float* q     = (float*)((char*)d_ws + q_off);              // N*8 f32
    size_t hb_off = ((q_off + (size_t)N * NCENT * 4 + 255) & ~(size_t)255);
    ushort_t* hb = (ushort_t*)((char*)d_ws + hb_off);          // N*512 bf16
    size_t hm_off = ((hb_off + (size_t)N * DIM * 2 + 255) & ~(size_t)255);
    float* hm    = (float*)((char*)d_ws + hm_off);             // N*512 f32
    size_t need  = hm_off + (size_t)N * DIM * sizeof(float);

    hipMemsetAsync(cnt, 0, (size_t)(N + 16) * sizeof(int), stream);

    if (ws_size >= need) {
        prep_kernel<<<(N + 3) / 4, 256, 0, stream>>>(h, Ws, hb, q, N);
        scatter_pad_kernel<<<(E + 255) / 256, 256, 0, stream>>>(esrc, edst, cnt, slots, E);
        gather_hb_kernel<<<N, 256, 0, stream>>>(hb, cnt, slots, Ws, hm, route,
                                                gcnt, nsus, suslist, N);
        fixup_kernel<<<(N + 3) / 4, 256, 0, stream>>>(q, cnt, slots, suslist,
                                                      nsus, route, gcnt, N);
        group_prep_kernel<<<1, 64, 0, stream>>>(gcnt, goff, gcur, tloff);
        group_scatter_kernel<<<(N + 255) / 256, 256, 0, stream>>>(route, gcur, nlist, N);
        int maxtiles = N / TM + NCENT + 1;
        gemm_kernel<<<maxtiles, 256, 0, stream>>>(hm, nlist, goff, tloff, Wt, out);
    } else {
        scatter_pad_kernel<<<(E + 255) / 256, 256, 0, stream>>>(esrc, edst, cnt, slots, E);
        node_kernel<<<N, 256, 0, stream>>>(h, cnt, slots, Ws, Wt, out);
    }
}

// Round 8
// 467.956 us; speedup vs baseline: 1.0431x; 1.0431x over previous
//
#include <hip/hip_runtime.h>

#define DIM    512
#define NCLS   128
#define NCENT  8
#define TM     64
#define KC     32
#define WSLOT  64      // padded neighbor-slot width (max degree guard)

typedef unsigned short ushort_t;
typedef unsigned int   uint_t;

static __device__ __forceinline__ ushort_t f2bf(float f) {
    uint_t x = __float_as_uint(f);
    uint_t r = (x + 0x7fffu + ((x >> 16) & 1u)) >> 16;   // RTNE (finite inputs)
    return (ushort_t)r;
}
static __device__ __forceinline__ float bf_lo(uint_t w) {
    return __uint_as_float(w << 16);
}
static __device__ __forceinline__ float bf_hi(uint_t w) {
    return __uint_as_float(w & 0xffff0000u);
}

// --- prep: hb = bf16(h); q = h @ Ws^T (f32, router-exact). Wave/node. --------

__global__ __launch_bounds__(256) void prep_kernel(const float* __restrict__ h,
                                                   const float* __restrict__ Ws,
                                                   ushort_t* __restrict__ hb,
                                                   float* __restrict__ q, int N) {
    int wid = (blockIdx.x * 256 + threadIdx.x) >> 6;   // node
    int lane = threadIdx.x & 63;
    if (wid >= N) return;                               // wave-uniform exit

    const float* row = h + (size_t)wid * DIM + lane * 8;
    float4 a = *(const float4*)row;
    float4 b = *(const float4*)(row + 4);
    float fa[8] = {a.x, a.y, a.z, a.w, b.x, b.y, b.z, b.w};

    union { ushort_t us[8]; uint4 v; } pk;
    #pragma unroll
    for (int i = 0; i < 8; ++i) pk.us[i] = f2bf(fa[i]);
    *(uint4*)(hb + (size_t)wid * DIM + lane * 8) = pk.v;

    float qv = 0.f;
    #pragma unroll
    for (int c = 0; c < NCENT; ++c) {
        const float* w = Ws + c * DIM + lane * 8;
        float4 w0 = *(const float4*)w;
        float4 w1 = *(const float4*)(w + 4);
        float p = fa[0]*w0.x + fa[1]*w0.y + fa[2]*w0.z + fa[3]*w0.w
                + fa[4]*w1.x + fa[5]*w1.y + fa[6]*w1.z + fa[7]*w1.w;
        #pragma unroll
        for (int s = 32; s > 0; s >>= 1) p += __shfl_xor(p, s, 64);
        if (lane == c) qv = p;
    }
    if (lane < NCENT) q[(size_t)wid * NCENT + lane] = qv;
}

// --- padded-slot CSR: one atomic pass ----------------------------------------

__global__ __launch_bounds__(256) void scatter_pad_kernel(const int* __restrict__ src,
                                                          const int* __restrict__ dst,
                                                          int* __restrict__ cnt,
                                                          int* __restrict__ slots, int E) {
    int i = blockIdx.x * 256 + threadIdx.x;
    if (i < E) {
        int d = dst[i];
        int k = atomicAdd(&cnt[d], 1);
        if (k < WSLOT) slots[(size_t)d * WSLOT + k] = src[i];
    }
}

// --- qroute2: one wave per node, lane = (c, jj). Deterministic f32 sums. -----
// score[c] = q[n][c] + sum_j q[sl[j]][c]; per-c partial over j==jj (mod 8),
// then 3-step shfl tree (fixed order). argmax = (max value, min index).

__global__ __launch_bounds__(256) void qroute2_kernel(
        const float* __restrict__ q, const int* __restrict__ cnt,
        const int* __restrict__ slots, int* __restrict__ route,
        int* __restrict__ gcnt, int N) {
    int w = (blockIdx.x * 256 + threadIdx.x) >> 6;     // node
    int lane = threadIdx.x & 63;
    if (w >= N) return;                                 // wave-uniform exit
    int c  = lane & 7;
    int jj = lane >> 3;                                 // 0..7

    int cn = cnt[w]; if (cn > WSLOT) cn = WSLOT;
    const int* sl = slots + (size_t)w * WSLOT;

    float s = 0.f;
    for (int j = jj; j < cn; j += 8)                    // avg 2 iters
        s += q[(size_t)sl[j] * NCENT + c];

    // reduce over jj (lanes spaced by 8): fixed pairwise tree
    s += __shfl_xor(s, 8, 64);
    s += __shfl_xor(s, 16, 64);
    s += __shfl_xor(s, 32, 64);
    s += q[(size_t)w * NCENT + c];                      // self loop

    // lex argmax over the 8 c-lanes of each group (value desc, index asc)
    float v = s; int idx = c;
    #pragma unroll
    for (int st = 1; st < 8; st <<= 1) {
        float ov = __shfl_xor(v, st, 64);
        int   oi = __shfl_xor(idx, st, 64);
        if (ov > v || (ov == v && oi < idx)) { v = ov; idx = oi; }
    }
    if (lane == 0) {
        route[w] = idx;
        atomicAdd(&gcnt[idx], 1);
    }
}

// --- group nodes by route ----------------------------------------------------

__global__ void group_prep_kernel(const int* __restrict__ gcnt,
                                  int* __restrict__ goff, int* __restrict__ gcur,
                                  int* __restrict__ tloff) {
    if (threadIdx.x == 0 && blockIdx.x == 0) {
        int g = 0, tt = 0;
        for (int c = 0; c < NCENT; ++c) {
            goff[c] = g; gcur[c] = g; tloff[c] = tt;
            g += gcnt[c]; tt += (gcnt[c] + TM - 1) / TM;
        }
        goff[NCENT] = g; tloff[NCENT] = tt;
    }
}

__global__ __launch_bounds__(256) void group_scatter_kernel(
        const int* __restrict__ route, int* __restrict__ gcur,
        int* __restrict__ nlist, int N) {
    int i = blockIdx.x * 256 + threadIdx.x;
    if (i < N) {
        int r = route[i];
        int p = atomicAdd(&gcur[r], 1);
        nlist[p] = i;
    }
}

// --- bf16 gather-mean, NO fused router (r4's fast version, verbatim). --------

__global__ __launch_bounds__(256) void gather_hb_kernel(
        const ushort_t* __restrict__ hb, const int* __restrict__ cnt,
        const int* __restrict__ slots, float* __restrict__ hm, int N) {
    int wid = (blockIdx.x * 256 + threadIdx.x) >> 6;   // node
    int lane = threadIdx.x & 63;
    if (wid >= N) return;

    int cn = cnt[wid]; if (cn > WSLOT) cn = WSLOT;
    int myslot = (lane < cn) ? slots[(size_t)wid * WSLOT + lane] : 0;

    float acc[8];
    {   // self loop
        uint4 u = *(const uint4*)(hb + (size_t)wid * DIM + lane * 8);
        acc[0] = bf_lo(u.x); acc[1] = bf_hi(u.x);
        acc[2] = bf_lo(u.y); acc[3] = bf_hi(u.y);
        acc[4] = bf_lo(u.z); acc[5] = bf_hi(u.z);
        acc[6] = bf_lo(u.w); acc[7] = bf_hi(u.w);
    }
    int j = 0;
    for (; j + 8 <= cn; j += 8) {
        uint4 u[8];
        #pragma unroll
        for (int k = 0; k < 8; ++k) {
            int s = __shfl(myslot, j + k, 64);
            u[k] = *(const uint4*)(hb + (size_t)s * DIM + lane * 8);
        }
        #pragma unroll
        for (int k = 0; k < 8; ++k) {
            acc[0] += bf_lo(u[k].x); acc[1] += bf_hi(u[k].x);
            acc[2] += bf_lo(u[k].y); acc[3] += bf_hi(u[k].y);
            acc[4] += bf_lo(u[k].z); acc[5] += bf_hi(u[k].z);
            acc[6] += bf_lo(u[k].w); acc[7] += bf_hi(u[k].w);
        }
    }
    for (; j < cn; ++j) {
        int s = __shfl(myslot, j, 64);
        uint4 u = *(const uint4*)(hb + (size_t)s * DIM + lane * 8);
        acc[0] += bf_lo(u.x); acc[1] += bf_hi(u.x);
        acc[2] += bf_lo(u.y); acc[3] += bf_hi(u.y);
        acc[4] += bf_lo(u.z); acc[5] += bf_hi(u.z);
        acc[6] += bf_lo(u.w); acc[7] += bf_hi(u.w);
    }
    float inv = 1.0f / (float)(cn + 1);
    #pragma unroll
    for (int k = 0; k < 8; ++k) acc[k] *= inv;
    float4 o0 = {acc[0], acc[1], acc[2], acc[3]};
    float4 o1 = {acc[4], acc[5], acc[6], acc[7]};
    float* dst = hm + (size_t)wid * DIM + lane * 8;
    *(float4*)dst = o0;
    *(float4*)(dst + 4) = o1;
}

// --- grouped GEMM  out[n, :] = hm[n, :] @ Wt[route(n)]^T ---------------------

__global__ __launch_bounds__(256) void gemm_kernel(
        const float* __restrict__ hm, const int* __restrict__ nlist,
        const int* __restrict__ goff, const int* __restrict__ tloff,
        const float* __restrict__ Wt, float* __restrict__ out) {
    __shared__ float a_s[TM][KC + 1];
    __shared__ float b_s[NCLS][KC + 1];

    int b = blockIdx.x;
    if (b >= tloff[NCENT]) return;
    int c = 0;
    while (b >= tloff[c + 1]) ++c;
    int row0 = goff[c] + (b - tloff[c]) * TM;
    int mrows = goff[c + 1] - row0; if (mrows > TM) mrows = TM;

    int tid = threadIdx.x;
    int tn = tid & 31;
    int tm = tid >> 5;

    float acc[8][4];
    #pragma unroll
    for (int i = 0; i < 8; ++i)
        #pragma unroll
        for (int j = 0; j < 4; ++j) acc[i][j] = 0.f;

    const float* wt_c = Wt + (size_t)c * NCLS * DIM;

    for (int k0 = 0; k0 < DIM; k0 += KC) {
        #pragma unroll
        for (int r = 0; r < 2; ++r) {
            int cidx = tid + 256 * r;
            int row = cidx >> 3;
            int kq = (cidx & 7) * 4;
            int rr = row < mrows ? row : mrows - 1;
            int nd = nlist[row0 + rr];
            float4 v = *(const float4*)(hm + (size_t)nd * DIM + k0 + kq);
            a_s[row][kq] = v.x; a_s[row][kq+1] = v.y;
            a_s[row][kq+2] = v.z; a_s[row][kq+3] = v.w;
        }
        #pragma unroll
        for (int r = 0; r < 4; ++r) {
            int cidx = tid + 256 * r;
            int row = cidx >> 3;
            int kq = (cidx & 7) * 4;
            float4 v = *(const float4*)(wt_c + (size_t)row * DIM + k0 + kq);
            b_s[row][kq] = v.x; b_s[row][kq+1] = v.y;
            b_s[row][kq+2] = v.z; b_s[row][kq+3] = v.w;
        }
        __syncthreads();
        #pragma unroll
        for (int k = 0; k < KC; ++k) {
            float bv[4];
            #pragma unroll
            for (int j = 0; j < 4; ++j) bv[j] = b_s[tn + 32 * j][k];
            #pragma unroll
            for (int i = 0; i < 8; ++i) {
                float av = a_s[tm * 8 + i][k];
                #pragma unroll
                for (int j = 0; j < 4; ++j) acc[i][j] += av * bv[j];
            }
        }
        __syncthreads();
    }

    #pragma unroll
    for (int i = 0; i < 8; ++i) {
        int row = tm * 8 + i;
        if (row < mrows) {
            int nd = nlist[row0 + row];
            #pragma unroll
            for (int j = 0; j < 4; ++j)
                out[(size_t)nd * NCLS + tn + 32 * j] = acc[i][j];
        }
    }
}

// --- Fallback: fused slots-based per-node kernel (f32 end-to-end) ------------

__global__ __launch_bounds__(256) void node_kernel(const float* __restrict__ h,
                                                   const int* __restrict__ cnt,
                                                   const int* __restrict__ slots,
                                                   const float* __restrict__ Ws,
                                                   const float* __restrict__ Wt,
                                                   float* __restrict__ out) {
    int node = blockIdx.x;
    int t = threadIdx.x;
    __shared__ float hm[DIM];
    __shared__ float sc[NCENT];
    __shared__ int route_s;

    int d0 = t * 2;
    float2 acc = *(const float2*)(h + (size_t)node * DIM + d0);
    int cn = cnt[node]; if (cn > WSLOT) cn = WSLOT;
    const int* sl = slots + (size_t)node * WSLOT;
    for (int j = 0; j < cn; ++j) {
        float2 v = *(const float2*)(h + (size_t)sl[j] * DIM + d0);
        acc.x += v.x; acc.y += v.y;
    }
    float inv = 1.0f / (float)(cn + 1);
    hm[d0] = acc.x * inv; hm[d0 + 1] = acc.y * inv;
    __syncthreads();
    if (t < NCENT) {
        const float* w = Ws + t * DIM;
        float s = 0.f;
        for (int d = 0; d < DIM; d += 4) {
            float4 a = *(const float4*)(&hm[d]);
            float4 b = *(const float4*)(w + d);
            s += a.x * b.x + a.y * b.y + a.z * b.z + a.w * b.w;
        }
        sc[t] = s;
    }
    __syncthreads();
    if (t == 0) {
        int best = 0; float bv = sc[0];
        #pragma unroll
        for (int c = 1; c < NCENT; ++c)
            if (sc[c] > bv) { bv = sc[c]; best = c; }
        route_s = best;
    }
    __syncthreads();
    int route = route_s;
    if (t < NCLS) {
        const float* w = Wt + ((size_t)route * NCLS + t) * DIM;
        float s = 0.f;
        for (int d = 0; d < DIM; d += 4) {
            float4 a = *(const float4*)(&hm[d]);
            float4 b = *(const float4*)(w + d);
            s += a.x * b.x + a.y * b.y + a.z * b.z + a.w * b.w;
        }
        out[(size_t)node * NCLS + t] = s;
    }
}

// --- launch ------------------------------------------------------------------

extern "C" void kernel_launch(void* const* d_in, const int* in_sizes, int n_in,
                              void* d_out, int out_size, void* d_ws, size_t ws_size,
                              hipStream_t stream) {
    const float* h   = (const float*)d_in[0];
    const int*   ei  = (const int*)d_in[1];
    const float* Ws  = (const float*)d_in[2];
    const float* Wt  = (const float*)d_in[3];
    float*       out = (float*)d_out;

    int N = in_sizes[0] / DIM;
    int E = in_sizes[1] / 2;
    const int* esrc = ei;
    const int* edst = ei + E;

    int* wsp    = (int*)d_ws;
    int* cnt    = wsp;                       // N
    int* gcnt   = cnt + N;                   // 8
    int* gcur   = gcnt + NCENT;              // 8
    int* route  = gcur + NCENT;              // N
    int* goff   = route + N;                 // 9
    int* tloff  = goff + NCENT + 1;          // 9
    int* nlist  = tloff + NCENT + 1;         // N
    int* slots  = nlist + N;                 // N*WSLOT
    size_t iw   = (size_t)(3 * N + 2 * NCENT + 2 * (NCENT + 1)) + (size_t)N * WSLOT;
    size_t q_off  = ((iw * 4 + 255) & ~(size_t)255);
    float* q    = (float*)((char*)d_ws + q_off);               // N*8 f32
    size_t hb_off = ((q_off + (size_t)N * NCENT * 4 + 255) & ~(size_t)255);
    ushort_t* hb = (ushort_t*)((char*)d_ws + hb_off);          // N*512 bf16
    size_t hm_off = ((hb_off + (size_t)N * DIM * 2 + 255) & ~(size_t)255);
    float* hm   = (float*)((char*)d_ws + hm_off);              // N*512 f32
    size_t need = hm_off + (size_t)N * DIM * sizeof(float);

    hipMemsetAsync(cnt, 0, (size_t)(N + 2 * NCENT) * sizeof(int), stream);

    if (ws_size >= need) {
        prep_kernel<<<(N + 3) / 4, 256, 0, stream>>>(h, Ws, hb, q, N);
        scatter_pad_kernel<<<(E + 255) / 256, 256, 0, stream>>>(esrc, edst, cnt, slots, E);
        qroute2_kernel<<<(N + 3) / 4, 256, 0, stream>>>(q, cnt, slots, route, gcnt, N);
        group_prep_kernel<<<1, 64, 0, stream>>>(gcnt, goff, gcur, tloff);
        group_scatter_kernel<<<(N + 255) / 256, 256, 0, stream>>>(route, gcur, nlist, N);
        gather_hb_kernel<<<(N + 3) / 4, 256, 0, stream>>>(hb, cnt, slots, hm, N);
        int maxtiles = N / TM + NCENT + 1;
        gemm_kernel<<<maxtiles, 256, 0, stream>>>(hm, nlist, goff, tloff, Wt, out);
    } else {
        scatter_pad_kernel<<<(E + 255) / 256, 256, 0, stream>>>(esrc, edst, cnt, slots, E);
        node_kernel<<<N, 256, 0, stream>>>(h, cnt, slots, Ws, Wt, out);
    }
}

// Round 9
// 245.747 us; speedup vs baseline: 1.9864x; 1.9042x over previous
//
#include <hip/hip_runtime.h>

#define DIM    512
#define NCLS   128
#define NCENT  8
#define TM     64
#define KC     32
#define WSLOT  64      // padded neighbor-slot width (max degree guard)

typedef unsigned short ushort_t;
typedef unsigned int   uint_t;

static __device__ __forceinline__ ushort_t f2bf(float f) {
    uint_t x = __float_as_uint(f);
    uint_t r = (x + 0x7fffu + ((x >> 16) & 1u)) >> 16;   // RTNE (finite inputs)
    return (ushort_t)r;
}
static __device__ __forceinline__ float bf_lo(uint_t w) {
    return __uint_as_float(w << 16);
}
static __device__ __forceinline__ float bf_hi(uint_t w) {
    return __uint_as_float(w & 0xffff0000u);
}

// --- prep: hb = bf16(h); q = h @ Ws^T (f32, router-exact). Wave/node. --------

__global__ __launch_bounds__(256) void prep_kernel(const float* __restrict__ h,
                                                   const float* __restrict__ Ws,
                                                   ushort_t* __restrict__ hb,
                                                   float* __restrict__ q, int N) {
    int wid = (blockIdx.x * 256 + threadIdx.x) >> 6;   // node
    int lane = threadIdx.x & 63;
    if (wid >= N) return;                               // wave-uniform exit

    const float* row = h + (size_t)wid * DIM + lane * 8;
    float4 a = *(const float4*)row;
    float4 b = *(const float4*)(row + 4);
    float fa[8] = {a.x, a.y, a.z, a.w, b.x, b.y, b.z, b.w};

    union { ushort_t us[8]; uint4 v; } pk;
    #pragma unroll
    for (int i = 0; i < 8; ++i) pk.us[i] = f2bf(fa[i]);
    *(uint4*)(hb + (size_t)wid * DIM + lane * 8) = pk.v;

    float qv = 0.f;
    #pragma unroll
    for (int c = 0; c < NCENT; ++c) {
        const float* w = Ws + c * DIM + lane * 8;
        float4 w0 = *(const float4*)w;
        float4 w1 = *(const float4*)(w + 4);
        float p = fa[0]*w0.x + fa[1]*w0.y + fa[2]*w0.z + fa[3]*w0.w
                + fa[4]*w1.x + fa[5]*w1.y + fa[6]*w1.z + fa[7]*w1.w;
        #pragma unroll
        for (int s = 32; s > 0; s >>= 1) p += __shfl_xor(p, s, 64);
        if (lane == c) qv = p;
    }
    if (lane < NCENT) q[(size_t)wid * NCENT + lane] = qv;
}

// --- padded-slot CSR: one atomic pass (cnt spread over 80KB — no hot line) ---

__global__ __launch_bounds__(256) void scatter_pad_kernel(const int* __restrict__ src,
                                                          const int* __restrict__ dst,
                                                          int* __restrict__ cnt,
                                                          int* __restrict__ slots, int E) {
    int i = blockIdx.x * 256 + threadIdx.x;
    if (i < E) {
        int d = dst[i];
        int k = atomicAdd(&cnt[d], 1);
        if (k < WSLOT) slots[(size_t)d * WSLOT + k] = src[i];
    }
}

// --- qroute2: one wave per node. NO global atomics (hot-line fix). -----------

__global__ __launch_bounds__(256) void qroute2_kernel(
        const float* __restrict__ q, const int* __restrict__ cnt,
        const int* __restrict__ slots, int* __restrict__ route, int N) {
    int w = (blockIdx.x * 256 + threadIdx.x) >> 6;     // node
    int lane = threadIdx.x & 63;
    if (w >= N) return;                                 // wave-uniform exit
    int c  = lane & 7;
    int jj = lane >> 3;                                 // 0..7

    int cn = cnt[w]; if (cn > WSLOT) cn = WSLOT;
    const int* sl = slots + (size_t)w * WSLOT;

    float s = 0.f;
    for (int j = jj; j < cn; j += 8)                    // avg 2 iters
        s += q[(size_t)sl[j] * NCENT + c];

    // reduce over jj (lanes spaced by 8): fixed pairwise tree
    s += __shfl_xor(s, 8, 64);
    s += __shfl_xor(s, 16, 64);
    s += __shfl_xor(s, 32, 64);
    s += q[(size_t)w * NCENT + c];                      // self loop

    // lex argmax over the 8 c-lanes (value desc, index asc) = first max
    float v = s; int idx = c;
    #pragma unroll
    for (int st = 1; st < 8; st <<= 1) {
        float ov = __shfl_xor(v, st, 64);
        int   oi = __shfl_xor(idx, st, 64);
        if (ov > v || (ov == v && oi < idx)) { v = ov; idx = oi; }
    }
    if (lane == 0) route[w] = idx;
}

// --- route histogram: per-block LDS bins, 8 batched atomics per block --------

__global__ __launch_bounds__(256) void route_hist_kernel(const int* __restrict__ route,
                                                         int* __restrict__ gcnt, int N) {
    __shared__ int lh[NCENT];
    int t = threadIdx.x;
    if (t < NCENT) lh[t] = 0;
    __syncthreads();
    for (int i = blockIdx.x * 256 + t; i < N; i += gridDim.x * 256)
        atomicAdd(&lh[route[i]], 1);
    __syncthreads();
    if (t < NCENT) atomicAdd(&gcnt[t], lh[t]);   // 8 lanes, one wave-request
}

// --- group nodes by route ----------------------------------------------------

__global__ void group_prep_kernel(const int* __restrict__ gcnt,
                                  int* __restrict__ goff, int* __restrict__ gcur,
                                  int* __restrict__ tloff) {
    if (threadIdx.x == 0 && blockIdx.x == 0) {
        int g = 0, tt = 0;
        for (int c = 0; c < NCENT; ++c) {
            goff[c] = g; gcur[c] = g; tloff[c] = tt;
            g += gcnt[c]; tt += (gcnt[c] + TM - 1) / TM;
        }
        goff[NCENT] = g; tloff[NCENT] = tt;
    }
}

__global__ __launch_bounds__(256) void group_scatter_kernel(
        const int* __restrict__ route, int* __restrict__ gcur,
        int* __restrict__ nlist, int N) {
    int i = blockIdx.x * 256 + threadIdx.x;
    if (i < N) {
        int r = route[i];
        int p = atomicAdd(&gcur[r], 1);   // 64 active lanes/wave-request: batched
        nlist[p] = i;
    }
}

// --- bf16 gather-mean, no router, no atomics (r4 fast version, verbatim) -----

__global__ __launch_bounds__(256) void gather_hb_kernel(
        const ushort_t* __restrict__ hb, const int* __restrict__ cnt,
        const int* __restrict__ slots, float* __restrict__ hm, int N) {
    int wid = (blockIdx.x * 256 + threadIdx.x) >> 6;   // node
    int lane = threadIdx.x & 63;
    if (wid >= N) return;

    int cn = cnt[wid]; if (cn > WSLOT) cn = WSLOT;
    int myslot = (lane < cn) ? slots[(size_t)wid * WSLOT + lane] : 0;

    float acc[8];
    {   // self loop
        uint4 u = *(const uint4*)(hb + (size_t)wid * DIM + lane * 8);
        acc[0] = bf_lo(u.x); acc[1] = bf_hi(u.x);
        acc[2] = bf_lo(u.y); acc[3] = bf_hi(u.y);
        acc[4] = bf_lo(u.z); acc[5] = bf_hi(u.z);
        acc[6] = bf_lo(u.w); acc[7] = bf_hi(u.w);
    }
    int j = 0;
    for (; j + 8 <= cn; j += 8) {
        uint4 u[8];
        #pragma unroll
        for (int k = 0; k < 8; ++k) {
            int s = __shfl(myslot, j + k, 64);
            u[k] = *(const uint4*)(hb + (size_t)s * DIM + lane * 8);
        }
        #pragma unroll
        for (int k = 0; k < 8; ++k) {
            acc[0] += bf_lo(u[k].x); acc[1] += bf_hi(u[k].x);
            acc[2] += bf_lo(u[k].y); acc[3] += bf_hi(u[k].y);
            acc[4] += bf_lo(u[k].z); acc[5] += bf_hi(u[k].z);
            acc[6] += bf_lo(u[k].w); acc[7] += bf_hi(u[k].w);
        }
    }
    for (; j < cn; ++j) {
        int s = __shfl(myslot, j, 64);
        uint4 u = *(const uint4*)(hb + (size_t)s * DIM + lane * 8);
        acc[0] += bf_lo(u.x); acc[1] += bf_hi(u.x);
        acc[2] += bf_lo(u.y); acc[3] += bf_hi(u.y);
        acc[4] += bf_lo(u.z); acc[5] += bf_hi(u.z);
        acc[6] += bf_lo(u.w); acc[7] += bf_hi(u.w);
    }
    float inv = 1.0f / (float)(cn + 1);
    #pragma unroll
    for (int k = 0; k < 8; ++k) acc[k] *= inv;
    float4 o0 = {acc[0], acc[1], acc[2], acc[3]};
    float4 o1 = {acc[4], acc[5], acc[6], acc[7]};
    float* dst = hm + (size_t)wid * DIM + lane * 8;
    *(float4*)dst = o0;
    *(float4*)(dst + 4) = o1;
}

// --- grouped GEMM  out[n, :] = hm[n, :] @ Wt[route(n)]^T ---------------------

__global__ __launch_bounds__(256) void gemm_kernel(
        const float* __restrict__ hm, const int* __restrict__ nlist,
        const int* __restrict__ goff, const int* __restrict__ tloff,
        const float* __restrict__ Wt, float* __restrict__ out) {
    __shared__ float a_s[TM][KC + 1];
    __shared__ float b_s[NCLS][KC + 1];

    int b = blockIdx.x;
    if (b >= tloff[NCENT]) return;
    int c = 0;
    while (b >= tloff[c + 1]) ++c;
    int row0 = goff[c] + (b - tloff[c]) * TM;
    int mrows = goff[c + 1] - row0; if (mrows > TM) mrows = TM;

    int tid = threadIdx.x;
    int tn = tid & 31;
    int tm = tid >> 5;

    float acc[8][4];
    #pragma unroll
    for (int i = 0; i < 8; ++i)
        #pragma unroll
        for (int j = 0; j < 4; ++j) acc[i][j] = 0.f;

    const float* wt_c = Wt + (size_t)c * NCLS * DIM;

    for (int k0 = 0; k0 < DIM; k0 += KC) {
        #pragma unroll
        for (int r = 0; r < 2; ++r) {
            int cidx = tid + 256 * r;
            int row = cidx >> 3;
            int kq = (cidx & 7) * 4;
            int rr = row < mrows ? row : mrows - 1;
            int nd = nlist[row0 + rr];
            float4 v = *(const float4*)(hm + (size_t)nd * DIM + k0 + kq);
            a_s[row][kq] = v.x; a_s[row][kq+1] = v.y;
            a_s[row][kq+2] = v.z; a_s[row][kq+3] = v.w;
        }
        #pragma unroll
        for (int r = 0; r < 4; ++r) {
            int cidx = tid + 256 * r;
            int row = cidx >> 3;
            int kq = (cidx & 7) * 4;
            float4 v = *(const float4*)(wt_c + (size_t)row * DIM + k0 + kq);
            b_s[row][kq] = v.x; b_s[row][kq+1] = v.y;
            b_s[row][kq+2] = v.z; b_s[row][kq+3] = v.w;
        }
        __syncthreads();
        #pragma unroll
        for (int k = 0; k < KC; ++k) {
            float bv[4];
            #pragma unroll
            for (int j = 0; j < 4; ++j) bv[j] = b_s[tn + 32 * j][k];
            #pragma unroll
            for (int i = 0; i < 8; ++i) {
                float av = a_s[tm * 8 + i][k];
                #pragma unroll
                for (int j = 0; j < 4; ++j) acc[i][j] += av * bv[j];
            }
        }
        __syncthreads();
    }

    #pragma unroll
    for (int i = 0; i < 8; ++i) {
        int row = tm * 8 + i;
        if (row < mrows) {
            int nd = nlist[row0 + row];
            #pragma unroll
            for (int j = 0; j < 4; ++j)
                out[(size_t)nd * NCLS + tn + 32 * j] = acc[i][j];
        }
    }
}

// --- Fallback: fused slots-based per-node kernel (f32 end-to-end) ------------

__global__ __launch_bounds__(256) void node_kernel(const float* __restrict__ h,
                                                   const int* __restrict__ cnt,
                                                   const int* __restrict__ slots,
                                                   const float* __restrict__ Ws,
                                                   const float* __restrict__ Wt,
                                                   float* __restrict__ out) {
    int node = blockIdx.x;
    int t = threadIdx.x;
    __shared__ float hm[DIM];
    __shared__ float sc[NCENT];
    __shared__ int route_s;

    int d0 = t * 2;
    float2 acc = *(const float2*)(h + (size_t)node * DIM + d0);
    int cn = cnt[node]; if (cn > WSLOT) cn = WSLOT;
    const int* sl = slots + (size_t)node * WSLOT;
    for (int j = 0; j < cn; ++j) {
        float2 v = *(const float2*)(h + (size_t)sl[j] * DIM + d0);
        acc.x += v.x; acc.y += v.y;
    }
    float inv = 1.0f / (float)(cn + 1);
    hm[d0] = acc.x * inv; hm[d0 + 1] = acc.y * inv;
    __syncthreads();
    if (t < NCENT) {
        const float* w = Ws + t * DIM;
        float s = 0.f;
        for (int d = 0; d < DIM; d += 4) {
            float4 a = *(const float4*)(&hm[d]);
            float4 b = *(const float4*)(w + d);
            s += a.x * b.x + a.y * b.y + a.z * b.z + a.w * b.w;
        }
        sc[t] = s;
    }
    __syncthreads();
    if (t == 0) {
        int best = 0; float bv = sc[0];
        #pragma unroll
        for (int c = 1; c < NCENT; ++c)
            if (sc[c] > bv) { bv = sc[c]; best = c; }
        route_s = best;
    }
    __syncthreads();
    int route = route_s;
    if (t < NCLS) {
        const float* w = Wt + ((size_t)route * NCLS + t) * DIM;
        float s = 0.f;
        for (int d = 0; d < DIM; d += 4) {
            float4 a = *(const float4*)(&hm[d]);
            float4 b = *(const float4*)(w + d);
            s += a.x * b.x + a.y * b.y + a.z * b.z + a.w * b.w;
        }
        out[(size_t)node * NCLS + t] = s;
    }
}

// --- launch ------------------------------------------------------------------

extern "C" void kernel_launch(void* const* d_in, const int* in_sizes, int n_in,
                              void* d_out, int out_size, void* d_ws, size_t ws_size,
                              hipStream_t stream) {
    const float* h   = (const float*)d_in[0];
    const int*   ei  = (const int*)d_in[1];
    const float* Ws  = (const float*)d_in[2];
    const float* Wt  = (const float*)d_in[3];
    float*       out = (float*)d_out;

    int N = in_sizes[0] / DIM;
    int E = in_sizes[1] / 2;
    const int* esrc = ei;
    const int* edst = ei + E;

    int* wsp    = (int*)d_ws;
    int* cnt    = wsp;                       // N
    int* gcnt   = cnt + N;                   // 8
    int* gcur   = gcnt + NCENT;              // 8
    int* route  = gcur + NCENT;              // N
    int* goff   = route + N;                 // 9
    int* tloff  = goff + NCENT + 1;          // 9
    int* nlist  = tloff + NCENT + 1;         // N
    int* slots  = nlist + N;                 // N*WSLOT
    size_t iw   = (size_t)(3 * N + 2 * NCENT + 2 * (NCENT + 1)) + (size_t)N * WSLOT;
    size_t q_off  = ((iw * 4 + 255) & ~(size_t)255);
    float* q    = (float*)((char*)d_ws + q_off);               // N*8 f32
    size_t hb_off = ((q_off + (size_t)N * NCENT * 4 + 255) & ~(size_t)255);
    ushort_t* hb = (ushort_t*)((char*)d_ws + hb_off);          // N*512 bf16
    size_t hm_off = ((hb_off + (size_t)N * DIM * 2 + 255) & ~(size_t)255);
    float* hm   = (float*)((char*)d_ws + hm_off);              // N*512 f32
    size_t need = hm_off + (size_t)N * DIM * sizeof(float);

    hipMemsetAsync(cnt, 0, (size_t)(N + 2 * NCENT) * sizeof(int), stream);

    if (ws_size >= need) {
        prep_kernel<<<(N + 3) / 4, 256, 0, stream>>>(h, Ws, hb, q, N);
        scatter_pad_kernel<<<(E + 255) / 256, 256, 0, stream>>>(esrc, edst, cnt, slots, E);
        qroute2_kernel<<<(N + 3) / 4, 256, 0, stream>>>(q, cnt, slots, route, N);
        route_hist_kernel<<<64, 256, 0, stream>>>(route, gcnt, N);
        group_prep_kernel<<<1, 64, 0, stream>>>(gcnt, goff, gcur, tloff);
        group_scatter_kernel<<<(N + 255) / 256, 256, 0, stream>>>(route, gcur, nlist, N);
        gather_hb_kernel<<<(N + 3) / 4, 256, 0, stream>>>(hb, cnt, slots, hm, N);
        int maxtiles = N / TM + NCENT + 1;
        gemm_kernel<<<maxtiles, 256, 0, stream>>>(hm, nlist, goff, tloff, Wt, out);
    } else {
        scatter_pad_kernel<<<(E + 255) / 256, 256, 0, stream>>>(esrc, edst, cnt, slots, E);
        node_kernel<<<N, 256, 0, stream>>>(h, cnt, slots, Ws, Wt, out);
    }
}

// Round 10
// 173.683 us; speedup vs baseline: 2.8105x; 1.4149x over previous
//
#include <hip/hip_runtime.h>

#define DIM    512
#define NCLS   128
#define NCENT  8
#define TM     64
#define KC     32
#define WSLOT  64      // padded neighbor-slot width (max degree guard)
#define NB     64      // fixed grid for hist/scan/scatter counting sort

typedef unsigned short ushort_t;
typedef unsigned int   uint_t;

static __device__ __forceinline__ ushort_t f2bf(float f) {
    uint_t x = __float_as_uint(f);
    uint_t r = (x + 0x7fffu + ((x >> 16) & 1u)) >> 16;   // RTNE (finite inputs)
    return (ushort_t)r;
}
static __device__ __forceinline__ float bf_lo(uint_t w) {
    return __uint_as_float(w << 16);
}
static __device__ __forceinline__ float bf_hi(uint_t w) {
    return __uint_as_float(w & 0xffff0000u);
}

// --- prep: hb = bf16(h); q = h @ Ws^T (f32, router-exact). Wave/node. --------

__global__ __launch_bounds__(256) void prep_kernel(const float* __restrict__ h,
                                                   const float* __restrict__ Ws,
                                                   ushort_t* __restrict__ hb,
                                                   float* __restrict__ q, int N) {
    int wid = (blockIdx.x * 256 + threadIdx.x) >> 6;   // node
    int lane = threadIdx.x & 63;
    if (wid >= N) return;                               // wave-uniform exit

    const float* row = h + (size_t)wid * DIM + lane * 8;
    float4 a = *(const float4*)row;
    float4 b = *(const float4*)(row + 4);
    float fa[8] = {a.x, a.y, a.z, a.w, b.x, b.y, b.z, b.w};

    union { ushort_t us[8]; uint4 v; } pk;
    #pragma unroll
    for (int i = 0; i < 8; ++i) pk.us[i] = f2bf(fa[i]);
    *(uint4*)(hb + (size_t)wid * DIM + lane * 8) = pk.v;

    float qv = 0.f;
    #pragma unroll
    for (int c = 0; c < NCENT; ++c) {
        const float* w = Ws + c * DIM + lane * 8;
        float4 w0 = *(const float4*)w;
        float4 w1 = *(const float4*)(w + 4);
        float p = fa[0]*w0.x + fa[1]*w0.y + fa[2]*w0.z + fa[3]*w0.w
                + fa[4]*w1.x + fa[5]*w1.y + fa[6]*w1.z + fa[7]*w1.w;
        #pragma unroll
        for (int s = 32; s > 0; s >>= 1) p += __shfl_xor(p, s, 64);
        if (lane == c) qv = p;
    }
    if (lane < NCENT) q[(size_t)wid * NCENT + lane] = qv;
}

// --- padded-slot CSR: one atomic pass (cnt spread over 80KB — no hot line) ---

__global__ __launch_bounds__(256) void scatter_pad_kernel(const int* __restrict__ src,
                                                          const int* __restrict__ dst,
                                                          int* __restrict__ cnt,
                                                          int* __restrict__ slots, int E) {
    int i = blockIdx.x * 256 + threadIdx.x;
    if (i < E) {
        int d = dst[i];
        int k = atomicAdd(&cnt[d], 1);
        if (k < WSLOT) slots[(size_t)d * WSLOT + k] = src[i];
    }
}

// --- qroute2: one wave per node. NO global atomics. --------------------------

__global__ __launch_bounds__(256) void qroute2_kernel(
        const float* __restrict__ q, const int* __restrict__ cnt,
        const int* __restrict__ slots, int* __restrict__ route, int N) {
    int w = (blockIdx.x * 256 + threadIdx.x) >> 6;     // node
    int lane = threadIdx.x & 63;
    if (w >= N) return;                                 // wave-uniform exit
    int c  = lane & 7;
    int jj = lane >> 3;                                 // 0..7

    int cn = cnt[w]; if (cn > WSLOT) cn = WSLOT;
    const int* sl = slots + (size_t)w * WSLOT;

    float s = 0.f;
    for (int j = jj; j < cn; j += 8)                    // avg 2 iters
        s += q[(size_t)sl[j] * NCENT + c];

    // reduce over jj (lanes spaced by 8): fixed pairwise tree
    s += __shfl_xor(s, 8, 64);
    s += __shfl_xor(s, 16, 64);
    s += __shfl_xor(s, 32, 64);
    s += q[(size_t)w * NCENT + c];                      // self loop

    // lex argmax over the 8 c-lanes (value desc, index asc) = first max
    float v = s; int idx = c;
    #pragma unroll
    for (int st = 1; st < 8; st <<= 1) {
        float ov = __shfl_xor(v, st, 64);
        int   oi = __shfl_xor(idx, st, 64);
        if (ov > v || (ov == v && oi < idx)) { v = ov; idx = oi; }
    }
    if (lane == 0) route[w] = idx;
}

// --- counting sort, phase 1: per-block 8-bin histogram (LDS only) ------------

__global__ __launch_bounds__(256) void route_hist_kernel(const int* __restrict__ route,
                                                         int* __restrict__ bhist, int N) {
    __shared__ int lh[NCENT];
    int t = threadIdx.x;
    if (t < NCENT) lh[t] = 0;
    __syncthreads();
    for (int i = blockIdx.x * 256 + t; i < N; i += NB * 256)
        atomicAdd(&lh[route[i]], 1);
    __syncthreads();
    if (t < NCENT) bhist[blockIdx.x * NCENT + t] = lh[t];
}

// --- counting sort, phase 2: scan bins -> goff/tloff/bbase (one block) -------

__global__ __launch_bounds__(512) void scan_bins_kernel(const int* __restrict__ bhist,
                                                        int* __restrict__ bbase,
                                                        int* __restrict__ goff,
                                                        int* __restrict__ tloff) {
    __shared__ int s[NCENT][NB];
    __shared__ int go[NCENT + 1], tl[NCENT + 1];
    int t = threadIdx.x;            // 512 = NB*NCENT
    int b = t >> 3, c = t & 7;
    int v = bhist[b * NCENT + c];
    s[c][b] = v;
    __syncthreads();
    for (int st = 1; st < NB; st <<= 1) {   // inclusive scan over b, per c
        int a = (b >= st) ? s[c][b - st] : 0;
        __syncthreads();
        s[c][b] += a;
        __syncthreads();
    }
    if (t == 0) {
        int g = 0, tt = 0;
        for (int cc = 0; cc < NCENT; ++cc) {
            go[cc] = g; tl[cc] = tt;
            int gc = s[cc][NB - 1];
            g += gc; tt += (gc + TM - 1) / TM;
        }
        go[NCENT] = g; tl[NCENT] = tt;
    }
    __syncthreads();
    bbase[b * NCENT + c] = go[c] + s[c][b] - v;      // exclusive + group base
    if (t < NCENT + 1) { goff[t] = go[t]; tloff[t] = tl[t]; }
}

// --- counting sort, phase 3: scatter with LDS cursors (same i-mapping) -------

__global__ __launch_bounds__(256) void group_scatter2_kernel(
        const int* __restrict__ route, const int* __restrict__ bbase,
        int* __restrict__ nlist, int N) {
    __shared__ int lcur[NCENT];
    int t = threadIdx.x;
    if (t < NCENT) lcur[t] = bbase[blockIdx.x * NCENT + t];
    __syncthreads();
    for (int i = blockIdx.x * 256 + t; i < N; i += NB * 256) {
        int p = atomicAdd(&lcur[route[i]], 1);       // LDS atomic — no hot L2 line
        nlist[p] = i;
    }
}

// --- bf16 gather-mean, no router, no atomics ---------------------------------

__global__ __launch_bounds__(256) void gather_hb_kernel(
        const ushort_t* __restrict__ hb, const int* __restrict__ cnt,
        const int* __restrict__ slots, float* __restrict__ hm, int N) {
    int wid = (blockIdx.x * 256 + threadIdx.x) >> 6;   // node
    int lane = threadIdx.x & 63;
    if (wid >= N) return;

    int cn = cnt[wid]; if (cn > WSLOT) cn = WSLOT;
    int myslot = (lane < cn) ? slots[(size_t)wid * WSLOT + lane] : 0;

    float acc[8];
    {   // self loop
        uint4 u = *(const uint4*)(hb + (size_t)wid * DIM + lane * 8);
        acc[0] = bf_lo(u.x); acc[1] = bf_hi(u.x);
        acc[2] = bf_lo(u.y); acc[3] = bf_hi(u.y);
        acc[4] = bf_lo(u.z); acc[5] = bf_hi(u.z);
        acc[6] = bf_lo(u.w); acc[7] = bf_hi(u.w);
    }
    int j = 0;
    for (; j + 8 <= cn; j += 8) {
        uint4 u[8];
        #pragma unroll
        for (int k = 0; k < 8; ++k) {
            int s = __shfl(myslot, j + k, 64);
            u[k] = *(const uint4*)(hb + (size_t)s * DIM + lane * 8);
        }
        #pragma unroll
        for (int k = 0; k < 8; ++k) {
            acc[0] += bf_lo(u[k].x); acc[1] += bf_hi(u[k].x);
            acc[2] += bf_lo(u[k].y); acc[3] += bf_hi(u[k].y);
            acc[4] += bf_lo(u[k].z); acc[5] += bf_hi(u[k].z);
            acc[6] += bf_lo(u[k].w); acc[7] += bf_hi(u[k].w);
        }
    }
    for (; j < cn; ++j) {
        int s = __shfl(myslot, j, 64);
        uint4 u = *(const uint4*)(hb + (size_t)s * DIM + lane * 8);
        acc[0] += bf_lo(u.x); acc[1] += bf_hi(u.x);
        acc[2] += bf_lo(u.y); acc[3] += bf_hi(u.y);
        acc[4] += bf_lo(u.z); acc[5] += bf_hi(u.z);
        acc[6] += bf_lo(u.w); acc[7] += bf_hi(u.w);
    }
    float inv = 1.0f / (float)(cn + 1);
    #pragma unroll
    for (int k = 0; k < 8; ++k) acc[k] *= inv;
    float4 o0 = {acc[0], acc[1], acc[2], acc[3]};
    float4 o1 = {acc[4], acc[5], acc[6], acc[7]};
    float* dst = hm + (size_t)wid * DIM + lane * 8;
    *(float4*)dst = o0;
    *(float4*)(dst + 4) = o1;
}

// --- grouped GEMM  out[n, :] = hm[n, :] @ Wt[route(n)]^T ---------------------

__global__ __launch_bounds__(256) void gemm_kernel(
        const float* __restrict__ hm, const int* __restrict__ nlist,
        const int* __restrict__ goff, const int* __restrict__ tloff,
        const float* __restrict__ Wt, float* __restrict__ out) {
    __shared__ float a_s[TM][KC + 1];
    __shared__ float b_s[NCLS][KC + 1];

    int b = blockIdx.x;
    if (b >= tloff[NCENT]) return;
    int c = 0;
    while (b >= tloff[c + 1]) ++c;
    int row0 = goff[c] + (b - tloff[c]) * TM;
    int mrows = goff[c + 1] - row0; if (mrows > TM) mrows = TM;

    int tid = threadIdx.x;
    int tn = tid & 31;
    int tm = tid >> 5;

    float acc[8][4];
    #pragma unroll
    for (int i = 0; i < 8; ++i)
        #pragma unroll
        for (int j = 0; j < 4; ++j) acc[i][j] = 0.f;

    const float* wt_c = Wt + (size_t)c * NCLS * DIM;

    for (int k0 = 0; k0 < DIM; k0 += KC) {
        #pragma unroll
        for (int r = 0; r < 2; ++r) {
            int cidx = tid + 256 * r;
            int row = cidx >> 3;
            int kq = (cidx & 7) * 4;
            int rr = row < mrows ? row : mrows - 1;
            int nd = nlist[row0 + rr];
            float4 v = *(const float4*)(hm + (size_t)nd * DIM + k0 + kq);
            a_s[row][kq] = v.x; a_s[row][kq+1] = v.y;
            a_s[row][kq+2] = v.z; a_s[row][kq+3] = v.w;
        }
        #pragma unroll
        for (int r = 0; r < 4; ++r) {
            int cidx = tid + 256 * r;
            int row = cidx >> 3;
            int kq = (cidx & 7) * 4;
            float4 v = *(const float4*)(wt_c + (size_t)row * DIM + k0 + kq);
            b_s[row][kq] = v.x; b_s[row][kq+1] = v.y;
            b_s[row][kq+2] = v.z; b_s[row][kq+3] = v.w;
        }
        __syncthreads();
        #pragma unroll
        for (int k = 0; k < KC; ++k) {
            float bv[4];
            #pragma unroll
            for (int j = 0; j < 4; ++j) bv[j] = b_s[tn + 32 * j][k];
            #pragma unroll
            for (int i = 0; i < 8; ++i) {
                float av = a_s[tm * 8 + i][k];
                #pragma unroll
                for (int j = 0; j < 4; ++j) acc[i][j] += av * bv[j];
            }
        }
        __syncthreads();
    }

    #pragma unroll
    for (int i = 0; i < 8; ++i) {
        int row = tm * 8 + i;
        if (row < mrows) {
            int nd = nlist[row0 + row];
            #pragma unroll
            for (int j = 0; j < 4; ++j)
                out[(size_t)nd * NCLS + tn + 32 * j] = acc[i][j];
        }
    }
}

// --- Fallback: fused slots-based per-node kernel (f32 end-to-end) ------------

__global__ __launch_bounds__(256) void node_kernel(const float* __restrict__ h,
                                                   const int* __restrict__ cnt,
                                                   const int* __restrict__ slots,
                                                   const float* __restrict__ Ws,
                                                   const float* __restrict__ Wt,
                                                   float* __restrict__ out) {
    int node = blockIdx.x;
    int t = threadIdx.x;
    __shared__ float hm[DIM];
    __shared__ float sc[NCENT];
    __shared__ int route_s;

    int d0 = t * 2;
    float2 acc = *(const float2*)(h + (size_t)node * DIM + d0);
    int cn = cnt[node]; if (cn > WSLOT) cn = WSLOT;
    const int* sl = slots + (size_t)node * WSLOT;
    for (int j = 0; j < cn; ++j) {
        float2 v = *(const float2*)(h + (size_t)sl[j] * DIM + d0);
        acc.x += v.x; acc.y += v.y;
    }
    float inv = 1.0f / (float)(cn + 1);
    hm[d0] = acc.x * inv; hm[d0 + 1] = acc.y * inv;
    __syncthreads();
    if (t < NCENT) {
        const float* w = Ws + t * DIM;
        float s = 0.f;
        for (int d = 0; d < DIM; d += 4) {
            float4 a = *(const float4*)(&hm[d]);
            float4 b = *(const float4*)(w + d);
            s += a.x * b.x + a.y * b.y + a.z * b.z + a.w * b.w;
        }
        sc[t] = s;
    }
    __syncthreads();
    if (t == 0) {
        int best = 0; float bv = sc[0];
        #pragma unroll
        for (int c = 1; c < NCENT; ++c)
            if (sc[c] > bv) { bv = sc[c]; best = c; }
        route_s = best;
    }
    __syncthreads();
    int route = route_s;
    if (t < NCLS) {
        const float* w = Wt + ((size_t)route * NCLS + t) * DIM;
        float s = 0.f;
        for (int d = 0; d < DIM; d += 4) {
            float4 a = *(const float4*)(&hm[d]);
            float4 b = *(const float4*)(w + d);
            s += a.x * b.x + a.y * b.y + a.z * b.z + a.w * b.w;
        }
        out[(size_t)node * NCLS + t] = s;
    }
}

// --- launch ------------------------------------------------------------------

extern "C" void kernel_launch(void* const* d_in, const int* in_sizes, int n_in,
                              void* d_out, int out_size, void* d_ws, size_t ws_size,
                              hipStream_t stream) {
    const float* h   = (const float*)d_in[0];
    const int*   ei  = (const int*)d_in[1];
    const float* Ws  = (const float*)d_in[2];
    const float* Wt  = (const float*)d_in[3];
    float*       out = (float*)d_out;

    int N = in_sizes[0] / DIM;
    int E = in_sizes[1] / 2;
    const int* esrc = ei;
    const int* edst = ei + E;

    int* wsp    = (int*)d_ws;
    int* cnt    = wsp;                       // N
    int* route  = cnt + N;                   // N
    int* goff   = route + N;                 // 9
    int* tloff  = goff + NCENT + 1;          // 9
    int* bhist  = tloff + NCENT + 1;         // NB*8
    int* bbase  = bhist + NB * NCENT;        // NB*8
    int* nlist  = bbase + NB * NCENT;        // N
    int* slots  = nlist + N;                 // N*WSLOT
    size_t iw   = (size_t)(3 * N) + 2 * (NCENT + 1) + 2 * NB * NCENT
                + (size_t)N * WSLOT;
    size_t q_off  = ((iw * 4 + 255) & ~(size_t)255);
    float* q    = (float*)((char*)d_ws + q_off);               // N*8 f32
    size_t hb_off = ((q_off + (size_t)N * NCENT * 4 + 255) & ~(size_t)255);
    ushort_t* hb = (ushort_t*)((char*)d_ws + hb_off);          // N*512 bf16
    size_t hm_off = ((hb_off + (size_t)N * DIM * 2 + 255) & ~(size_t)255);
    float* hm   = (float*)((char*)d_ws + hm_off);              // N*512 f32
    size_t need = hm_off + (size_t)N * DIM * sizeof(float);

    hipMemsetAsync(cnt, 0, (size_t)N * sizeof(int), stream);

    if (ws_size >= need) {
        prep_kernel<<<(N + 3) / 4, 256, 0, stream>>>(h, Ws, hb, q, N);
        scatter_pad_kernel<<<(E + 255) / 256, 256, 0, stream>>>(esrc, edst, cnt, slots, E);
        qroute2_kernel<<<(N + 3) / 4, 256, 0, stream>>>(q, cnt, slots, route, N);
        route_hist_kernel<<<NB, 256, 0, stream>>>(route, bhist, N);
        scan_bins_kernel<<<1, 512, 0, stream>>>(bhist, bbase, goff, tloff);
        group_scatter2_kernel<<<NB, 256, 0, stream>>>(route, bbase, nlist, N);
        gather_hb_kernel<<<(N + 3) / 4, 256, 0, stream>>>(hb, cnt, slots, hm, N);
        int maxtiles = N / TM + NCENT + 1;
        gemm_kernel<<<maxtiles, 256, 0, stream>>>(hm, nlist, goff, tloff, Wt, out);
    } else {
        scatter_pad_kernel<<<(E + 255) / 256, 256, 0, stream>>>(esrc, edst, cnt, slots, E);
        node_kernel<<<N, 256, 0, stream>>>(h, cnt, slots, Ws, Wt, out);
    }
}

// Round 11
// 165.577 us; speedup vs baseline: 2.9481x; 1.0490x over previous
//
#include <hip/hip_runtime.h>

#define DIM    512
#define NCLS   128
#define NCENT  8
#define TM     64
#define KC     32
#define WSLOT  64      // padded neighbor-slot width (max degree guard)
#define NB     64      // fixed grid for hist/scan/scatter counting sort
#define KSPLIT 4       // K-split factor for gemm (512/4 = 128 per slice)

typedef unsigned short ushort_t;
typedef unsigned int   uint_t;

static __device__ __forceinline__ ushort_t f2bf(float f) {
    uint_t x = __float_as_uint(f);
    uint_t r = (x + 0x7fffu + ((x >> 16) & 1u)) >> 16;   // RTNE (finite inputs)
    return (ushort_t)r;
}
static __device__ __forceinline__ float bf_lo(uint_t w) {
    return __uint_as_float(w << 16);
}
static __device__ __forceinline__ float bf_hi(uint_t w) {
    return __uint_as_float(w & 0xffff0000u);
}

// --- prep: hb = bf16(h); q = h @ Ws^T (f32, router-exact). Wave/node. --------

__global__ __launch_bounds__(256) void prep_kernel(const float* __restrict__ h,
                                                   const float* __restrict__ Ws,
                                                   ushort_t* __restrict__ hb,
                                                   float* __restrict__ q, int N) {
    int wid = (blockIdx.x * 256 + threadIdx.x) >> 6;   // node
    int lane = threadIdx.x & 63;
    if (wid >= N) return;                               // wave-uniform exit

    const float* row = h + (size_t)wid * DIM + lane * 8;
    float4 a = *(const float4*)row;
    float4 b = *(const float4*)(row + 4);
    float fa[8] = {a.x, a.y, a.z, a.w, b.x, b.y, b.z, b.w};

    union { ushort_t us[8]; uint4 v; } pk;
    #pragma unroll
    for (int i = 0; i < 8; ++i) pk.us[i] = f2bf(fa[i]);
    *(uint4*)(hb + (size_t)wid * DIM + lane * 8) = pk.v;

    float qv = 0.f;
    #pragma unroll
    for (int c = 0; c < NCENT; ++c) {
        const float* w = Ws + c * DIM + lane * 8;
        float4 w0 = *(const float4*)w;
        float4 w1 = *(const float4*)(w + 4);
        float p = fa[0]*w0.x + fa[1]*w0.y + fa[2]*w0.z + fa[3]*w0.w
                + fa[4]*w1.x + fa[5]*w1.y + fa[6]*w1.z + fa[7]*w1.w;
        #pragma unroll
        for (int s = 32; s > 0; s >>= 1) p += __shfl_xor(p, s, 64);
        if (lane == c) qv = p;
    }
    if (lane < NCENT) q[(size_t)wid * NCENT + lane] = qv;
}

// --- padded-slot CSR: one atomic pass (cnt spread over 80KB — no hot line) ---

__global__ __launch_bounds__(256) void scatter_pad_kernel(const int* __restrict__ src,
                                                          const int* __restrict__ dst,
                                                          int* __restrict__ cnt,
                                                          int* __restrict__ slots, int E) {
    int i = blockIdx.x * 256 + threadIdx.x;
    if (i < E) {
        int d = dst[i];
        int k = atomicAdd(&cnt[d], 1);
        if (k < WSLOT) slots[(size_t)d * WSLOT + k] = src[i];
    }
}

// --- qroute2: one wave per node. NO global atomics. --------------------------

__global__ __launch_bounds__(256) void qroute2_kernel(
        const float* __restrict__ q, const int* __restrict__ cnt,
        const int* __restrict__ slots, int* __restrict__ route, int N) {
    int w = (blockIdx.x * 256 + threadIdx.x) >> 6;     // node
    int lane = threadIdx.x & 63;
    if (w >= N) return;                                 // wave-uniform exit
    int c  = lane & 7;
    int jj = lane >> 3;                                 // 0..7

    int cn = cnt[w]; if (cn > WSLOT) cn = WSLOT;
    const int* sl = slots + (size_t)w * WSLOT;

    float s = 0.f;
    for (int j = jj; j < cn; j += 8)                    // avg 2 iters
        s += q[(size_t)sl[j] * NCENT + c];

    // reduce over jj (lanes spaced by 8): fixed pairwise tree
    s += __shfl_xor(s, 8, 64);
    s += __shfl_xor(s, 16, 64);
    s += __shfl_xor(s, 32, 64);
    s += q[(size_t)w * NCENT + c];                      // self loop

    // lex argmax over the 8 c-lanes (value desc, index asc) = first max
    float v = s; int idx = c;
    #pragma unroll
    for (int st = 1; st < 8; st <<= 1) {
        float ov = __shfl_xor(v, st, 64);
        int   oi = __shfl_xor(idx, st, 64);
        if (ov > v || (ov == v && oi < idx)) { v = ov; idx = oi; }
    }
    if (lane == 0) route[w] = idx;
}

// --- counting sort, phase 1: per-block 8-bin histogram (LDS only) ------------

__global__ __launch_bounds__(256) void route_hist_kernel(const int* __restrict__ route,
                                                         int* __restrict__ bhist, int N) {
    __shared__ int lh[NCENT];
    int t = threadIdx.x;
    if (t < NCENT) lh[t] = 0;
    __syncthreads();
    for (int i = blockIdx.x * 256 + t; i < N; i += NB * 256)
        atomicAdd(&lh[route[i]], 1);
    __syncthreads();
    if (t < NCENT) bhist[blockIdx.x * NCENT + t] = lh[t];
}

// --- counting sort, phase 2: scan bins -> goff/tloff/bbase (one block) -------

__global__ __launch_bounds__(512) void scan_bins_kernel(const int* __restrict__ bhist,
                                                        int* __restrict__ bbase,
                                                        int* __restrict__ goff,
                                                        int* __restrict__ tloff) {
    __shared__ int s[NCENT][NB];
    __shared__ int go[NCENT + 1], tl[NCENT + 1];
    int t = threadIdx.x;            // 512 = NB*NCENT
    int b = t >> 3, c = t & 7;
    int v = bhist[b * NCENT + c];
    s[c][b] = v;
    __syncthreads();
    for (int st = 1; st < NB; st <<= 1) {   // inclusive scan over b, per c
        int a = (b >= st) ? s[c][b - st] : 0;
        __syncthreads();
        s[c][b] += a;
        __syncthreads();
    }
    if (t == 0) {
        int g = 0, tt = 0;
        for (int cc = 0; cc < NCENT; ++cc) {
            go[cc] = g; tl[cc] = tt;
            int gc = s[cc][NB - 1];
            g += gc; tt += (gc + TM - 1) / TM;
        }
        go[NCENT] = g; tl[NCENT] = tt;
    }
    __syncthreads();
    bbase[b * NCENT + c] = go[c] + s[c][b] - v;      // exclusive + group base
    if (t < NCENT + 1) { goff[t] = go[t]; tloff[t] = tl[t]; }
}

// --- counting sort, phase 3: scatter with LDS cursors (same i-mapping) -------

__global__ __launch_bounds__(256) void group_scatter2_kernel(
        const int* __restrict__ route, const int* __restrict__ bbase,
        int* __restrict__ nlist, int N) {
    __shared__ int lcur[NCENT];
    int t = threadIdx.x;
    if (t < NCENT) lcur[t] = bbase[blockIdx.x * NCENT + t];
    __syncthreads();
    for (int i = blockIdx.x * 256 + t; i < N; i += NB * 256) {
        int p = atomicAdd(&lcur[route[i]], 1);       // LDS atomic — no hot L2 line
        nlist[p] = i;
    }
}

// --- bf16 gather-mean, no router, no atomics ---------------------------------

__global__ __launch_bounds__(256) void gather_hb_kernel(
        const ushort_t* __restrict__ hb, const int* __restrict__ cnt,
        const int* __restrict__ slots, float* __restrict__ hm, int N) {
    int wid = (blockIdx.x * 256 + threadIdx.x) >> 6;   // node
    int lane = threadIdx.x & 63;
    if (wid >= N) return;

    int cn = cnt[wid]; if (cn > WSLOT) cn = WSLOT;
    int myslot = (lane < cn) ? slots[(size_t)wid * WSLOT + lane] : 0;

    float acc[8];
    {   // self loop
        uint4 u = *(const uint4*)(hb + (size_t)wid * DIM + lane * 8);
        acc[0] = bf_lo(u.x); acc[1] = bf_hi(u.x);
        acc[2] = bf_lo(u.y); acc[3] = bf_hi(u.y);
        acc[4] = bf_lo(u.z); acc[5] = bf_hi(u.z);
        acc[6] = bf_lo(u.w); acc[7] = bf_hi(u.w);
    }
    int j = 0;
    for (; j + 8 <= cn; j += 8) {
        uint4 u[8];
        #pragma unroll
        for (int k = 0; k < 8; ++k) {
            int s = __shfl(myslot, j + k, 64);
            u[k] = *(const uint4*)(hb + (size_t)s * DIM + lane * 8);
        }
        #pragma unroll
        for (int k = 0; k < 8; ++k) {
            acc[0] += bf_lo(u[k].x); acc[1] += bf_hi(u[k].x);
            acc[2] += bf_lo(u[k].y); acc[3] += bf_hi(u[k].y);
            acc[4] += bf_lo(u[k].z); acc[5] += bf_hi(u[k].z);
            acc[6] += bf_lo(u[k].w); acc[7] += bf_hi(u[k].w);
        }
    }
    for (; j < cn; ++j) {
        int s = __shfl(myslot, j, 64);
        uint4 u = *(const uint4*)(hb + (size_t)s * DIM + lane * 8);
        acc[0] += bf_lo(u.x); acc[1] += bf_hi(u.x);
        acc[2] += bf_lo(u.y); acc[3] += bf_hi(u.y);
        acc[4] += bf_lo(u.z); acc[5] += bf_hi(u.z);
        acc[6] += bf_lo(u.w); acc[7] += bf_hi(u.w);
    }
    float inv = 1.0f / (float)(cn + 1);
    #pragma unroll
    for (int k = 0; k < 8; ++k) acc[k] *= inv;
    float4 o0 = {acc[0], acc[1], acc[2], acc[3]};
    float4 o1 = {acc[4], acc[5], acc[6], acc[7]};
    float* dst = hm + (size_t)wid * DIM + lane * 8;
    *(float4*)dst = o0;
    *(float4*)(dst + 4) = o1;
}

// --- grouped GEMM, split-K: pt[ks][n,:] = hm[n, Kslice] @ Wt[route]^T --------

__global__ __launch_bounds__(256) void gemm_split_kernel(
        const float* __restrict__ hm, const int* __restrict__ nlist,
        const int* __restrict__ goff, const int* __restrict__ tloff,
        const float* __restrict__ Wt, float* __restrict__ pt, int N) {
    __shared__ float a_s[TM][KC + 1];
    __shared__ float b_s[NCLS][KC + 1];

    int b = blockIdx.x;
    if (b >= tloff[NCENT]) return;
    int ks = blockIdx.y;                       // K-slice [ks*128, ks*128+128)
    int c = 0;
    while (b >= tloff[c + 1]) ++c;
    int row0 = goff[c] + (b - tloff[c]) * TM;
    int mrows = goff[c + 1] - row0; if (mrows > TM) mrows = TM;

    int tid = threadIdx.x;
    int tn = tid & 31;
    int tm = tid >> 5;

    float acc[8][4];
    #pragma unroll
    for (int i = 0; i < 8; ++i)
        #pragma unroll
        for (int j = 0; j < 4; ++j) acc[i][j] = 0.f;

    const float* wt_c = Wt + (size_t)c * NCLS * DIM;
    int kbeg = ks * (DIM / KSPLIT);
    int kend = kbeg + (DIM / KSPLIT);

    for (int k0 = kbeg; k0 < kend; k0 += KC) {
        #pragma unroll
        for (int r = 0; r < 2; ++r) {
            int cidx = tid + 256 * r;
            int row = cidx >> 3;
            int kq = (cidx & 7) * 4;
            int rr = row < mrows ? row : mrows - 1;
            int nd = nlist[row0 + rr];
            float4 v = *(const float4*)(hm + (size_t)nd * DIM + k0 + kq);
            a_s[row][kq] = v.x; a_s[row][kq+1] = v.y;
            a_s[row][kq+2] = v.z; a_s[row][kq+3] = v.w;
        }
        #pragma unroll
        for (int r = 0; r < 4; ++r) {
            int cidx = tid + 256 * r;
            int row = cidx >> 3;
            int kq = (cidx & 7) * 4;
            float4 v = *(const float4*)(wt_c + (size_t)row * DIM + k0 + kq);
            b_s[row][kq] = v.x; b_s[row][kq+1] = v.y;
            b_s[row][kq+2] = v.z; b_s[row][kq+3] = v.w;
        }
        __syncthreads();
        #pragma unroll
        for (int k = 0; k < KC; ++k) {
            float bv[4];
            #pragma unroll
            for (int j = 0; j < 4; ++j) bv[j] = b_s[tn + 32 * j][k];
            #pragma unroll
            for (int i = 0; i < 8; ++i) {
                float av = a_s[tm * 8 + i][k];
                #pragma unroll
                for (int j = 0; j < 4; ++j) acc[i][j] += av * bv[j];
            }
        }
        __syncthreads();
    }

    float* pts = pt + (size_t)ks * N * NCLS;
    #pragma unroll
    for (int i = 0; i < 8; ++i) {
        int row = tm * 8 + i;
        if (row < mrows) {
            int nd = nlist[row0 + row];
            #pragma unroll
            for (int j = 0; j < 4; ++j)
                pts[(size_t)nd * NCLS + tn + 32 * j] = acc[i][j];
        }
    }
}

// --- reduce partials: out = pt[0] + pt[1] + pt[2] + pt[3] (fixed order) ------

__global__ __launch_bounds__(256) void reduce_kernel(const float* __restrict__ pt,
                                                     float* __restrict__ out, int N) {
    size_t total = (size_t)N * NCLS / 4;       // float4 count
    size_t stride = (size_t)N * NCLS / 4;
    const float4* p = (const float4*)pt;
    float4* o = (float4*)out;
    for (size_t i = blockIdx.x * 256 + threadIdx.x; i < total;
         i += (size_t)gridDim.x * 256) {
        float4 a = p[i];
        float4 b = p[i + stride];
        float4 cc = p[i + 2 * stride];
        float4 d = p[i + 3 * stride];
        float4 r;
        r.x = (a.x + b.x) + (cc.x + d.x);
        r.y = (a.y + b.y) + (cc.y + d.y);
        r.z = (a.z + b.z) + (cc.z + d.z);
        r.w = (a.w + b.w) + (cc.w + d.w);
        o[i] = r;
    }
}

// --- grouped GEMM, single-K (fallback when partials don't fit) ---------------

__global__ __launch_bounds__(256) void gemm_kernel(
        const float* __restrict__ hm, const int* __restrict__ nlist,
        const int* __restrict__ goff, const int* __restrict__ tloff,
        const float* __restrict__ Wt, float* __restrict__ out) {
    __shared__ float a_s[TM][KC + 1];
    __shared__ float b_s[NCLS][KC + 1];

    int b = blockIdx.x;
    if (b >= tloff[NCENT]) return;
    int c = 0;
    while (b >= tloff[c + 1]) ++c;
    int row0 = goff[c] + (b - tloff[c]) * TM;
    int mrows = goff[c + 1] - row0; if (mrows > TM) mrows = TM;

    int tid = threadIdx.x;
    int tn = tid & 31;
    int tm = tid >> 5;

    float acc[8][4];
    #pragma unroll
    for (int i = 0; i < 8; ++i)
        #pragma unroll
        for (int j = 0; j < 4; ++j) acc[i][j] = 0.f;

    const float* wt_c = Wt + (size_t)c * NCLS * DIM;

    for (int k0 = 0; k0 < DIM; k0 += KC) {
        #pragma unroll
        for (int r = 0; r < 2; ++r) {
            int cidx = tid + 256 * r;
            int row = cidx >> 3;
            int kq = (cidx & 7) * 4;
            int rr = row < mrows ? row : mrows - 1;
            int nd = nlist[row0 + rr];
            float4 v = *(const float4*)(hm + (size_t)nd * DIM + k0 + kq);
            a_s[row][kq] = v.x; a_s[row][kq+1] = v.y;
            a_s[row][kq+2] = v.z; a_s[row][kq+3] = v.w;
        }
        #pragma unroll
        for (int r = 0; r < 4; ++r) {
            int cidx = tid + 256 * r;
            int row = cidx >> 3;
            int kq = (cidx & 7) * 4;
            float4 v = *(const float4*)(wt_c + (size_t)row * DIM + k0 + kq);
            b_s[row][kq] = v.x; b_s[row][kq+1] = v.y;
            b_s[row][kq+2] = v.z; b_s[row][kq+3] = v.w;
        }
        __syncthreads();
        #pragma unroll
        for (int k = 0; k < KC; ++k) {
            float bv[4];
            #pragma unroll
            for (int j = 0; j < 4; ++j) bv[j] = b_s[tn + 32 * j][k];
            #pragma unroll
            for (int i = 0; i < 8; ++i) {
                float av = a_s[tm * 8 + i][k];
                #pragma unroll
                for (int j = 0; j < 4; ++j) acc[i][j] += av * bv[j];
            }
        }
        __syncthreads();
    }

    #pragma unroll
    for (int i = 0; i < 8; ++i) {
        int row = tm * 8 + i;
        if (row < mrows) {
            int nd = nlist[row0 + row];
            #pragma unroll
            for (int j = 0; j < 4; ++j)
                out[(size_t)nd * NCLS + tn + 32 * j] = acc[i][j];
        }
    }
}

// --- Fallback: fused slots-based per-node kernel (f32 end-to-end) ------------

__global__ __launch_bounds__(256) void node_kernel(const float* __restrict__ h,
                                                   const int* __restrict__ cnt,
                                                   const int* __restrict__ slots,
                                                   const float* __restrict__ Ws,
                                                   const float* __restrict__ Wt,
                                                   float* __restrict__ out) {
    int node = blockIdx.x;
    int t = threadIdx.x;
    __shared__ float hm[DIM];
    __shared__ float sc[NCENT];
    __shared__ int route_s;

    int d0 = t * 2;
    float2 acc = *(const float2*)(h + (size_t)node * DIM + d0);
    int cn = cnt[node]; if (cn > WSLOT) cn = WSLOT;
    const int* sl = slots + (size_t)node * WSLOT;
    for (int j = 0; j < cn; ++j) {
        float2 v = *(const float2*)(h + (size_t)sl[j] * DIM + d0);
        acc.x += v.x; acc.y += v.y;
    }
    float inv = 1.0f / (float)(cn + 1);
    hm[d0] = acc.x * inv; hm[d0 + 1] = acc.y * inv;
    __syncthreads();
    if (t < NCENT) {
        const float* w = Ws + t * DIM;
        float s = 0.f;
        for (int d = 0; d < DIM; d += 4) {
            float4 a = *(const float4*)(&hm[d]);
            float4 b = *(const float4*)(w + d);
            s += a.x * b.x + a.y * b.y + a.z * b.z + a.w * b.w;
        }
        sc[t] = s;
    }
    __syncthreads();
    if (t == 0) {
        int best = 0; float bv = sc[0];
        #pragma unroll
        for (int c = 1; c < NCENT; ++c)
            if (sc[c] > bv) { bv = sc[c]; best = c; }
        route_s = best;
    }
    __syncthreads();
    int route = route_s;
    if (t < NCLS) {
        const float* w = Wt + ((size_t)route * NCLS + t) * DIM;
        float s = 0.f;
        for (int d = 0; d < DIM; d += 4) {
            float4 a = *(const float4*)(&hm[d]);
            float4 b = *(const float4*)(w + d);
            s += a.x * b.x + a.y * b.y + a.z * b.z + a.w * b.w;
        }
        out[(size_t)node * NCLS + t] = s;
    }
}

// --- launch ------------------------------------------------------------------

extern "C" void kernel_launch(void* const* d_in, const int* in_sizes, int n_in,
                              void* d_out, int out_size, void* d_ws, size_t ws_size,
                              hipStream_t stream) {
    const float* h   = (const float*)d_in[0];
    const int*   ei  = (const int*)d_in[1];
    const float* Ws  = (const float*)d_in[2];
    const float* Wt  = (const float*)d_in[3];
    float*       out = (float*)d_out;

    int N = in_sizes[0] / DIM;
    int E = in_sizes[1] / 2;
    const int* esrc = ei;
    const int* edst = ei + E;

    int* wsp    = (int*)d_ws;
    int* cnt    = wsp;                       // N
    int* route  = cnt + N;                   // N
    int* goff   = route + N;                 // 9
    int* tloff  = goff + NCENT + 1;          // 9
    int* bhist  = tloff + NCENT + 1;         // NB*8
    int* bbase  = bhist + NB * NCENT;        // NB*8
    int* nlist  = bbase + NB * NCENT;        // N
    int* slots  = nlist + N;                 // N*WSLOT
    size_t iw   = (size_t)(3 * N) + 2 * (NCENT + 1) + 2 * NB * NCENT
                + (size_t)N * WSLOT;
    size_t q_off  = ((iw * 4 + 255) & ~(size_t)255);
    float* q    = (float*)((char*)d_ws + q_off);               // N*8 f32
    size_t hb_off = ((q_off + (size_t)N * NCENT * 4 + 255) & ~(size_t)255);
    ushort_t* hb = (ushort_t*)((char*)d_ws + hb_off);          // N*512 bf16
    size_t hm_off = ((hb_off + (size_t)N * DIM * 2 + 255) & ~(size_t)255);
    float* hm   = (float*)((char*)d_ws + hm_off);              // N*512 f32
    size_t need = hm_off + (size_t)N * DIM * sizeof(float);
    size_t pt_off = ((need + 255) & ~(size_t)255);
    float* pt   = (float*)((char*)d_ws + pt_off);              // KSPLIT*N*128 f32
    size_t need2 = pt_off + (size_t)KSPLIT * N * NCLS * sizeof(float);

    hipMemsetAsync(cnt, 0, (size_t)N * sizeof(int), stream);

    if (ws_size >= need) {
        prep_kernel<<<(N + 3) / 4, 256, 0, stream>>>(h, Ws, hb, q, N);
        scatter_pad_kernel<<<(E + 255) / 256, 256, 0, stream>>>(esrc, edst, cnt, slots, E);
        qroute2_kernel<<<(N + 3) / 4, 256, 0, stream>>>(q, cnt, slots, route, N);
        route_hist_kernel<<<NB, 256, 0, stream>>>(route, bhist, N);
        scan_bins_kernel<<<1, 512, 0, stream>>>(bhist, bbase, goff, tloff);
        group_scatter2_kernel<<<NB, 256, 0, stream>>>(route, bbase, nlist, N);
        gather_hb_kernel<<<(N + 3) / 4, 256, 0, stream>>>(hb, cnt, slots, hm, N);
        int maxtiles = N / TM + NCENT + 1;
        if (ws_size >= need2) {
            dim3 g(maxtiles, KSPLIT);
            gemm_split_kernel<<<g, 256, 0, stream>>>(hm, nlist, goff, tloff, Wt, pt, N);
            reduce_kernel<<<2048, 256, 0, stream>>>(pt, out, N);
        } else {
            gemm_kernel<<<maxtiles, 256, 0, stream>>>(hm, nlist, goff, tloff, Wt, out);
        }
    } else {
        scatter_pad_kernel<<<(E + 255) / 256, 256, 0, stream>>>(esrc, edst, cnt, slots, E);
        node_kernel<<<N, 256, 0, stream>>>(h, cnt, slots, Ws, Wt, out);
    }
}

// Round 12
// 118.960 us; speedup vs baseline: 4.1034x; 1.3919x over previous
//
#include <hip/hip_runtime.h>

#define DIM    512
#define NCLS   128
#define NCENT  8
#define TM     64
#define WSLOT  64      // padded neighbor-slot width (max degree guard)
#define NB     64      // fixed grid for hist/scan/scatter counting sort
#define KC2    64      // K-chunk staged in LDS for MFMA gemm
#define KP2    72      // padded LDS row stride in bf16 (144B: 2-way bank alias = free)

typedef unsigned short ushort_t;
typedef unsigned int   uint_t;
typedef __attribute__((ext_vector_type(8))) short bf16x8;   // 8 bf16 (4 VGPRs)
typedef __attribute__((ext_vector_type(4))) float f32x4;    // MFMA C/D

static __device__ __forceinline__ ushort_t f2bf(float f) {
    uint_t x = __float_as_uint(f);
    uint_t r = (x + 0x7fffu + ((x >> 16) & 1u)) >> 16;   // RTNE (finite inputs)
    return (ushort_t)r;
}
static __device__ __forceinline__ float bf_lo(uint_t w) {
    return __uint_as_float(w << 16);
}
static __device__ __forceinline__ float bf_hi(uint_t w) {
    return __uint_as_float(w & 0xffff0000u);
}

// --- prep: hb = bf16(h); q = h @ Ws^T (f32, router-exact). Wave/node. --------

__global__ __launch_bounds__(256) void prep_kernel(const float* __restrict__ h,
                                                   const float* __restrict__ Ws,
                                                   ushort_t* __restrict__ hb,
                                                   float* __restrict__ q, int N) {
    int wid = (blockIdx.x * 256 + threadIdx.x) >> 6;   // node
    int lane = threadIdx.x & 63;
    if (wid >= N) return;                               // wave-uniform exit

    const float* row = h + (size_t)wid * DIM + lane * 8;
    float4 a = *(const float4*)row;
    float4 b = *(const float4*)(row + 4);
    float fa[8] = {a.x, a.y, a.z, a.w, b.x, b.y, b.z, b.w};

    union { ushort_t us[8]; uint4 v; } pk;
    #pragma unroll
    for (int i = 0; i < 8; ++i) pk.us[i] = f2bf(fa[i]);
    *(uint4*)(hb + (size_t)wid * DIM + lane * 8) = pk.v;

    float qv = 0.f;
    #pragma unroll
    for (int c = 0; c < NCENT; ++c) {
        const float* w = Ws + c * DIM + lane * 8;
        float4 w0 = *(const float4*)w;
        float4 w1 = *(const float4*)(w + 4);
        float p = fa[0]*w0.x + fa[1]*w0.y + fa[2]*w0.z + fa[3]*w0.w
                + fa[4]*w1.x + fa[5]*w1.y + fa[6]*w1.z + fa[7]*w1.w;
        #pragma unroll
        for (int s = 32; s > 0; s >>= 1) p += __shfl_xor(p, s, 64);
        if (lane == c) qv = p;
    }
    if (lane < NCENT) q[(size_t)wid * NCENT + lane] = qv;
}

// --- wtprep: wtb = bf16(Wt) --------------------------------------------------

__global__ __launch_bounds__(256) void wtprep_kernel(const float* __restrict__ Wt,
                                                     ushort_t* __restrict__ wtb,
                                                     int total8) {
    int i = blockIdx.x * 256 + threadIdx.x;            // one 8-elem chunk each
    if (i >= total8) return;
    const float* src = Wt + (size_t)i * 8;
    float4 a = *(const float4*)src;
    float4 b = *(const float4*)(src + 4);
    union { ushort_t us[8]; uint4 v; } pk;
    pk.us[0] = f2bf(a.x); pk.us[1] = f2bf(a.y);
    pk.us[2] = f2bf(a.z); pk.us[3] = f2bf(a.w);
    pk.us[4] = f2bf(b.x); pk.us[5] = f2bf(b.y);
    pk.us[6] = f2bf(b.z); pk.us[7] = f2bf(b.w);
    *(uint4*)(wtb + (size_t)i * 8) = pk.v;
}

// --- padded-slot CSR: one atomic pass (cnt spread over 80KB — no hot line) ---

__global__ __launch_bounds__(256) void scatter_pad_kernel(const int* __restrict__ src,
                                                          const int* __restrict__ dst,
                                                          int* __restrict__ cnt,
                                                          int* __restrict__ slots, int E) {
    int i = blockIdx.x * 256 + threadIdx.x;
    if (i < E) {
        int d = dst[i];
        int k = atomicAdd(&cnt[d], 1);
        if (k < WSLOT) slots[(size_t)d * WSLOT + k] = src[i];
    }
}

// --- qroute2: one wave per node. NO global atomics. --------------------------

__global__ __launch_bounds__(256) void qroute2_kernel(
        const float* __restrict__ q, const int* __restrict__ cnt,
        const int* __restrict__ slots, int* __restrict__ route, int N) {
    int w = (blockIdx.x * 256 + threadIdx.x) >> 6;     // node
    int lane = threadIdx.x & 63;
    if (w >= N) return;                                 // wave-uniform exit
    int c  = lane & 7;
    int jj = lane >> 3;                                 // 0..7

    int cn = cnt[w]; if (cn > WSLOT) cn = WSLOT;
    const int* sl = slots + (size_t)w * WSLOT;

    float s = 0.f;
    for (int j = jj; j < cn; j += 8)                    // avg 2 iters
        s += q[(size_t)sl[j] * NCENT + c];

    s += __shfl_xor(s, 8, 64);
    s += __shfl_xor(s, 16, 64);
    s += __shfl_xor(s, 32, 64);
    s += q[(size_t)w * NCENT + c];                      // self loop

    // lex argmax over the 8 c-lanes (value desc, index asc) = first max
    float v = s; int idx = c;
    #pragma unroll
    for (int st = 1; st < 8; st <<= 1) {
        float ov = __shfl_xor(v, st, 64);
        int   oi = __shfl_xor(idx, st, 64);
        if (ov > v || (ov == v && oi < idx)) { v = ov; idx = oi; }
    }
    if (lane == 0) route[w] = idx;
}

// --- counting sort, phase 1: per-block 8-bin histogram (LDS only) ------------

__global__ __launch_bounds__(256) void route_hist_kernel(const int* __restrict__ route,
                                                         int* __restrict__ bhist, int N) {
    __shared__ int lh[NCENT];
    int t = threadIdx.x;
    if (t < NCENT) lh[t] = 0;
    __syncthreads();
    for (int i = blockIdx.x * 256 + t; i < N; i += NB * 256)
        atomicAdd(&lh[route[i]], 1);
    __syncthreads();
    if (t < NCENT) bhist[blockIdx.x * NCENT + t] = lh[t];
}

// --- counting sort, phase 2: scan bins -> goff/tloff/bbase (one block) -------

__global__ __launch_bounds__(512) void scan_bins_kernel(const int* __restrict__ bhist,
                                                        int* __restrict__ bbase,
                                                        int* __restrict__ goff,
                                                        int* __restrict__ tloff) {
    __shared__ int s[NCENT][NB];
    __shared__ int go[NCENT + 1], tl[NCENT + 1];
    int t = threadIdx.x;            // 512 = NB*NCENT
    int b = t >> 3, c = t & 7;
    int v = bhist[b * NCENT + c];
    s[c][b] = v;
    __syncthreads();
    for (int st = 1; st < NB; st <<= 1) {   // inclusive scan over b, per c
        int a = (b >= st) ? s[c][b - st] : 0;
        __syncthreads();
        s[c][b] += a;
        __syncthreads();
    }
    if (t == 0) {
        int g = 0, tt = 0;
        for (int cc = 0; cc < NCENT; ++cc) {
            go[cc] = g; tl[cc] = tt;
            int gc = s[cc][NB - 1];
            g += gc; tt += (gc + TM - 1) / TM;
        }
        go[NCENT] = g; tl[NCENT] = tt;
    }
    __syncthreads();
    bbase[b * NCENT + c] = go[c] + s[c][b] - v;      // exclusive + group base
    if (t < NCENT + 1) { goff[t] = go[t]; tloff[t] = tl[t]; }
}

// --- counting sort, phase 3: scatter with LDS cursors ------------------------

__global__ __launch_bounds__(256) void group_scatter2_kernel(
        const int* __restrict__ route, const int* __restrict__ bbase,
        int* __restrict__ nlist, int N) {
    __shared__ int lcur[NCENT];
    int t = threadIdx.x;
    if (t < NCENT) lcur[t] = bbase[blockIdx.x * NCENT + t];
    __syncthreads();
    for (int i = blockIdx.x * 256 + t; i < N; i += NB * 256) {
        int p = atomicAdd(&lcur[route[i]], 1);       // LDS atomic — no hot L2 line
        nlist[p] = i;
    }
}

// --- bf16 gather-mean -> bf16 hmb. One wave per node. ------------------------

__global__ __launch_bounds__(256) void gather_hb_kernel(
        const ushort_t* __restrict__ hb, const int* __restrict__ cnt,
        const int* __restrict__ slots, ushort_t* __restrict__ hmb, int N) {
    int wid = (blockIdx.x * 256 + threadIdx.x) >> 6;   // node
    int lane = threadIdx.x & 63;
    if (wid >= N) return;

    int cn = cnt[wid]; if (cn > WSLOT) cn = WSLOT;
    int myslot = (lane < cn) ? slots[(size_t)wid * WSLOT + lane] : 0;

    float acc[8];
    {   // self loop
        uint4 u = *(const uint4*)(hb + (size_t)wid * DIM + lane * 8);
        acc[0] = bf_lo(u.x); acc[1] = bf_hi(u.x);
        acc[2] = bf_lo(u.y); acc[3] = bf_hi(u.y);
        acc[4] = bf_lo(u.z); acc[5] = bf_hi(u.z);
        acc[6] = bf_lo(u.w); acc[7] = bf_hi(u.w);
    }
    int j = 0;
    for (; j + 8 <= cn; j += 8) {
        uint4 u[8];
        #pragma unroll
        for (int k = 0; k < 8; ++k) {
            int s = __shfl(myslot, j + k, 64);
            u[k] = *(const uint4*)(hb + (size_t)s * DIM + lane * 8);
        }
        #pragma unroll
        for (int k = 0; k < 8; ++k) {
            acc[0] += bf_lo(u[k].x); acc[1] += bf_hi(u[k].x);
            acc[2] += bf_lo(u[k].y); acc[3] += bf_hi(u[k].y);
            acc[4] += bf_lo(u[k].z); acc[5] += bf_hi(u[k].z);
            acc[6] += bf_lo(u[k].w); acc[7] += bf_hi(u[k].w);
        }
    }
    for (; j < cn; ++j) {
        int s = __shfl(myslot, j, 64);
        uint4 u = *(const uint4*)(hb + (size_t)s * DIM + lane * 8);
        acc[0] += bf_lo(u.x); acc[1] += bf_hi(u.x);
        acc[2] += bf_lo(u.y); acc[3] += bf_hi(u.y);
        acc[4] += bf_lo(u.z); acc[5] += bf_hi(u.z);
        acc[6] += bf_lo(u.w); acc[7] += bf_hi(u.w);
    }
    float inv = 1.0f / (float)(cn + 1);
    union { ushort_t us[8]; uint4 v; } pk;
    #pragma unroll
    for (int k = 0; k < 8; ++k) pk.us[k] = f2bf(acc[k] * inv);
    *(uint4*)(hmb + (size_t)wid * DIM + lane * 8) = pk.v;
}

// --- grouped GEMM via bf16 MFMA: out[n,:] = hmb[n,:] @ wtb[route]^T ----------
// Tile 64 nodes x 128 outs; K staged in 64-chunks; 4 waves each own a 16-row
// band x 128 cols (8 mfma_f32_16x16x32_bf16 col-tiles, 2 k-steps per chunk).
// A/B frag: elem j of lane l = [row|col]=(l&15), k = (l>>4)*8 + j.
// C/D frag: col = l&15, row = (l>>4)*4 + reg (m89/m91-verified).

__global__ __launch_bounds__(256) void gemm_mfma_kernel(
        const ushort_t* __restrict__ hmb, const int* __restrict__ nlist,
        const int* __restrict__ goff, const int* __restrict__ tloff,
        const ushort_t* __restrict__ wtb, float* __restrict__ out) {
    __shared__ ushort_t a_s[TM * KP2];      // 9216 B
    __shared__ ushort_t b_s[NCLS * KP2];    // 18432 B
    __shared__ int nl_s[TM];

    int b = blockIdx.x;
    if (b >= tloff[NCENT]) return;
    int c = 0;
    while (b >= tloff[c + 1]) ++c;
    int row0 = goff[c] + (b - tloff[c]) * TM;
    int mrows = goff[c + 1] - row0; if (mrows > TM) mrows = TM;

    int tid = threadIdx.x;
    int wv = tid >> 6;                      // wave: rows [wv*16, wv*16+16)
    int lane = tid & 63;

    if (tid < TM) nl_s[tid] = nlist[row0 + (tid < mrows ? tid : mrows - 1)];
    __syncthreads();

    f32x4 acc[8];
    #pragma unroll
    for (int t = 0; t < 8; ++t) acc[t] = (f32x4){0.f, 0.f, 0.f, 0.f};

    const ushort_t* wt_c = wtb + (size_t)c * NCLS * DIM;

    for (int k0 = 0; k0 < DIM; k0 += KC2) {
        #pragma unroll
        for (int r = 0; r < 2; ++r) {               // stage A: 64x64 bf16
            int idx = tid + 256 * r;                // 0..511
            int row = idx >> 3;
            int kq = (idx & 7) * 8;
            int nd = nl_s[row];
            uint4 v = *(const uint4*)(hmb + (size_t)nd * DIM + k0 + kq);
            *(uint4*)&a_s[row * KP2 + kq] = v;
        }
        #pragma unroll
        for (int r = 0; r < 4; ++r) {               // stage B: 128x64 bf16
            int idx = tid + 256 * r;                // 0..1023
            int row = idx >> 3;
            int kq = (idx & 7) * 8;
            uint4 v = *(const uint4*)(wt_c + (size_t)row * DIM + k0 + kq);
            *(uint4*)&b_s[row * KP2 + kq] = v;
        }
        __syncthreads();
        #pragma unroll
        for (int s = 0; s < 2; ++s) {               // two K=32 steps
            int kof = s * 32 + (lane >> 4) * 8;
            bf16x8 af = *(const bf16x8*)&a_s[(wv * 16 + (lane & 15)) * KP2 + kof];
            #pragma unroll
            for (int t = 0; t < 8; ++t) {
                bf16x8 bf = *(const bf16x8*)&b_s[(t * 16 + (lane & 15)) * KP2 + kof];
                acc[t] = __builtin_amdgcn_mfma_f32_16x16x32_bf16(af, bf, acc[t], 0, 0, 0);
            }
        }
        __syncthreads();
    }

    #pragma unroll
    for (int r4 = 0; r4 < 4; ++r4) {
        int row = wv * 16 + (lane >> 4) * 4 + r4;
        if (row < mrows) {
            int nd = nl_s[row];
            float* orow = out + (size_t)nd * NCLS + (lane & 15);
            #pragma unroll
            for (int t = 0; t < 8; ++t)
                orow[t * 16] = acc[t][r4];
        }
    }
}

// --- Fallback: fused slots-based per-node kernel (f32 end-to-end) ------------

__global__ __launch_bounds__(256) void node_kernel(const float* __restrict__ h,
                                                   const int* __restrict__ cnt,
                                                   const int* __restrict__ slots,
                                                   const float* __restrict__ Ws,
                                                   const float* __restrict__ Wt,
                                                   float* __restrict__ out) {
    int node = blockIdx.x;
    int t = threadIdx.x;
    __shared__ float hm[DIM];
    __shared__ float sc[NCENT];
    __shared__ int route_s;

    int d0 = t * 2;
    float2 acc = *(const float2*)(h + (size_t)node * DIM + d0);
    int cn = cnt[node]; if (cn > WSLOT) cn = WSLOT;
    const int* sl = slots + (size_t)node * WSLOT;
    for (int j = 0; j < cn; ++j) {
        float2 v = *(const float2*)(h + (size_t)sl[j] * DIM + d0);
        acc.x += v.x; acc.y += v.y;
    }
    float inv = 1.0f / (float)(cn + 1);
    hm[d0] = acc.x * inv; hm[d0 + 1] = acc.y * inv;
    __syncthreads();
    if (t < NCENT) {
        const float* w = Ws + t * DIM;
        float s = 0.f;
        for (int d = 0; d < DIM; d += 4) {
            float4 a = *(const float4*)(&hm[d]);
            float4 b = *(const float4*)(w + d);
            s += a.x * b.x + a.y * b.y + a.z * b.z + a.w * b.w;
        }
        sc[t] = s;
    }
    __syncthreads();
    if (t == 0) {
        int best = 0; float bv = sc[0];
        #pragma unroll
        for (int c = 1; c < NCENT; ++c)
            if (sc[c] > bv) { bv = sc[c]; best = c; }
        route_s = best;
    }
    __syncthreads();
    int route = route_s;
    if (t < NCLS) {
        const float* w = Wt + ((size_t)route * NCLS + t) * DIM;
        float s = 0.f;
        for (int d = 0; d < DIM; d += 4) {
            float4 a = *(const float4*)(&hm[d]);
            float4 b = *(const float4*)(w + d);
            s += a.x * b.x + a.y * b.y + a.z * b.z + a.w * b.w;
        }
        out[(size_t)node * NCLS + t] = s;
    }
}

// --- launch ------------------------------------------------------------------

extern "C" void kernel_launch(void* const* d_in, const int* in_sizes, int n_in,
                              void* d_out, int out_size, void* d_ws, size_t ws_size,
                              hipStream_t stream) {
    const float* h   = (const float*)d_in[0];
    const int*   ei  = (const int*)d_in[1];
    const float* Ws  = (const float*)d_in[2];
    const float* Wt  = (const float*)d_in[3];
    float*       out = (float*)d_out;

    int N = in_sizes[0] / DIM;
    int E = in_sizes[1] / 2;
    int wt_elems = in_sizes[3];              // 8*128*512
    const int* esrc = ei;
    const int* edst = ei + E;

    int* wsp    = (int*)d_ws;
    int* cnt    = wsp;                       // N
    int* route  = cnt + N;                   // N
    int* goff   = route + N;                 // 9
    int* tloff  = goff + NCENT + 1;          // 9
    int* bhist  = tloff + NCENT + 1;         // NB*8
    int* bbase  = bhist + NB * NCENT;        // NB*8
    int* nlist  = bbase + NB * NCENT;        // N
    int* slots  = nlist + N;                 // N*WSLOT
    size_t iw   = (size_t)(3 * N) + 2 * (NCENT + 1) + 2 * NB * NCENT
                + (size_t)N * WSLOT;
    size_t q_off  = ((iw * 4 + 255) & ~(size_t)255);
    float* q    = (float*)((char*)d_ws + q_off);               // N*8 f32
    size_t hb_off = ((q_off + (size_t)N * NCENT * 4 + 255) & ~(size_t)255);
    ushort_t* hb = (ushort_t*)((char*)d_ws + hb_off);          // N*512 bf16
    size_t hmb_off = ((hb_off + (size_t)N * DIM * 2 + 255) & ~(size_t)255);
    ushort_t* hmb = (ushort_t*)((char*)d_ws + hmb_off);        // N*512 bf16
    size_t wtb_off = ((hmb_off + (size_t)N * DIM * 2 + 255) & ~(size_t)255);
    ushort_t* wtb = (ushort_t*)((char*)d_ws + wtb_off);        // 8*128*512 bf16
    size_t need = wtb_off + (size_t)wt_elems * 2;

    hipMemsetAsync(cnt, 0, (size_t)N * sizeof(int), stream);

    if (ws_size >= need) {
        prep_kernel<<<(N + 3) / 4, 256, 0, stream>>>(h, Ws, hb, q, N);
        wtprep_kernel<<<(wt_elems / 8 + 255) / 256, 256, 0, stream>>>(Wt, wtb, wt_elems / 8);
        scatter_pad_kernel<<<(E + 255) / 256, 256, 0, stream>>>(esrc, edst, cnt, slots, E);
        qroute2_kernel<<<(N + 3) / 4, 256, 0, stream>>>(q, cnt, slots, route, N);
        route_hist_kernel<<<NB, 256, 0, stream>>>(route, bhist, N);
        scan_bins_kernel<<<1, 512, 0, stream>>>(bhist, bbase, goff, tloff);
        group_scatter2_kernel<<<NB, 256, 0, stream>>>(route, bbase, nlist, N);
        gather_hb_kernel<<<(N + 3) / 4, 256, 0, stream>>>(hb, cnt, slots, hmb, N);
        int maxtiles = N / TM + NCENT + 1;
        gemm_mfma_kernel<<<maxtiles, 256, 0, stream>>>(hmb, nlist, goff, tloff, wtb, out);
    } else {
        scatter_pad_kernel<<<(E + 255) / 256, 256, 0, stream>>>(esrc, edst, cnt, slots, E);
        node_kernel<<<N, 256, 0, stream>>>(h, cnt, slots, Ws, Wt, out);
    }
}

// Round 13
// 114.332 us; speedup vs baseline: 4.2695x; 1.0405x over previous
//
#include <hip/hip_runtime.h>

#define DIM    512
#define NCLS   128
#define NCENT  8
#define TM     64
#define WSLOT  64      // padded neighbor-slot width (max degree guard)
#define NB     64      // fixed grid for hist/scan/scatter counting sort
#define KC2    64      // K-chunk staged in LDS for MFMA gemm
#define KP2    72      // padded LDS row stride in bf16 (144B: 2-way bank alias = free)

typedef unsigned short ushort_t;
typedef unsigned int   uint_t;
typedef __attribute__((ext_vector_type(8))) short bf16x8;   // 8 bf16 (4 VGPRs)
typedef __attribute__((ext_vector_type(4))) float f32x4;    // MFMA C/D

static __device__ __forceinline__ ushort_t f2bf(float f) {
    uint_t x = __float_as_uint(f);
    uint_t r = (x + 0x7fffu + ((x >> 16) & 1u)) >> 16;   // RTNE (finite inputs)
    return (ushort_t)r;
}
static __device__ __forceinline__ float bf_lo(uint_t w) {
    return __uint_as_float(w << 16);
}
static __device__ __forceinline__ float bf_hi(uint_t w) {
    return __uint_as_float(w & 0xffff0000u);
}

// --- prep (+Wt transcode tail blocks): hb = bf16(h); q = h @ Ws^T (f32). -----

__global__ __launch_bounds__(256) void prep_kernel(const float* __restrict__ h,
                                                   const float* __restrict__ Ws,
                                                   const float* __restrict__ Wt,
                                                   ushort_t* __restrict__ hb,
                                                   float* __restrict__ q,
                                                   ushort_t* __restrict__ wtb,
                                                   int N, int nprep, int total8) {
    if ((int)blockIdx.x >= nprep) {                     // Wt -> bf16 transcode
        int i = (blockIdx.x - nprep) * 256 + threadIdx.x;
        if (i < total8) {
            const float* src = Wt + (size_t)i * 8;
            float4 a = *(const float4*)src;
            float4 b = *(const float4*)(src + 4);
            union { ushort_t us[8]; uint4 v; } pk;
            pk.us[0] = f2bf(a.x); pk.us[1] = f2bf(a.y);
            pk.us[2] = f2bf(a.z); pk.us[3] = f2bf(a.w);
            pk.us[4] = f2bf(b.x); pk.us[5] = f2bf(b.y);
            pk.us[6] = f2bf(b.z); pk.us[7] = f2bf(b.w);
            *(uint4*)(wtb + (size_t)i * 8) = pk.v;
        }
        return;
    }
    int wid = (blockIdx.x * 256 + threadIdx.x) >> 6;   // node
    int lane = threadIdx.x & 63;
    if (wid >= N) return;                               // wave-uniform exit

    const float* row = h + (size_t)wid * DIM + lane * 8;
    float4 a = *(const float4*)row;
    float4 b = *(const float4*)(row + 4);
    float fa[8] = {a.x, a.y, a.z, a.w, b.x, b.y, b.z, b.w};

    union { ushort_t us[8]; uint4 v; } pk;
    #pragma unroll
    for (int i = 0; i < 8; ++i) pk.us[i] = f2bf(fa[i]);
    *(uint4*)(hb + (size_t)wid * DIM + lane * 8) = pk.v;

    float qv = 0.f;
    #pragma unroll
    for (int c = 0; c < NCENT; ++c) {
        const float* w = Ws + c * DIM + lane * 8;
        float4 w0 = *(const float4*)w;
        float4 w1 = *(const float4*)(w + 4);
        float p = fa[0]*w0.x + fa[1]*w0.y + fa[2]*w0.z + fa[3]*w0.w
                + fa[4]*w1.x + fa[5]*w1.y + fa[6]*w1.z + fa[7]*w1.w;
        #pragma unroll
        for (int s = 32; s > 0; s >>= 1) p += __shfl_xor(p, s, 64);
        if (lane == c) qv = p;
    }
    if (lane < NCENT) q[(size_t)wid * NCENT + lane] = qv;
}

// --- padded-slot CSR: one atomic pass (cnt spread over 80KB — no hot line) ---

__global__ __launch_bounds__(256) void scatter_pad_kernel(const int* __restrict__ src,
                                                          const int* __restrict__ dst,
                                                          int* __restrict__ cnt,
                                                          int* __restrict__ slots, int E) {
    int i = blockIdx.x * 256 + threadIdx.x;
    if (i < E) {
        int d = dst[i];
        int k = atomicAdd(&cnt[d], 1);
        if (k < WSLOT) slots[(size_t)d * WSLOT + k] = src[i];
    }
}

// --- gather-mean (bf16) + fused f32 q-router (NO global atomics). ------------
// Route math identical to round-6's validated version (64-lane tree + lane0
// self-row add + strict-> argmax); the r6 slowness was the gcnt hot-line
// atomic (proven r8), which is absent here.

__global__ __launch_bounds__(256) void gather_route_kernel(
        const ushort_t* __restrict__ hb, const int* __restrict__ cnt,
        const int* __restrict__ slots, const float* __restrict__ q,
        ushort_t* __restrict__ hmb, int* __restrict__ route, int N) {
    int wid = (blockIdx.x * 256 + threadIdx.x) >> 6;   // node
    int lane = threadIdx.x & 63;
    if (wid >= N) return;

    int cn = cnt[wid]; if (cn > WSLOT) cn = WSLOT;
    int myslot = (lane < cn) ? slots[(size_t)wid * WSLOT + lane] : 0;

    // early q-row load for my slot (overlaps with the gather below)
    float qs[NCENT];
    if (lane < cn) {
        const float* qr = q + (size_t)myslot * NCENT;
        float4 q0 = *(const float4*)qr;
        float4 q1 = *(const float4*)(qr + 4);
        qs[0]=q0.x; qs[1]=q0.y; qs[2]=q0.z; qs[3]=q0.w;
        qs[4]=q1.x; qs[5]=q1.y; qs[6]=q1.z; qs[7]=q1.w;
    } else {
        #pragma unroll
        for (int c = 0; c < NCENT; ++c) qs[c] = 0.f;
    }

    float acc[8];
    {   // self loop
        uint4 u = *(const uint4*)(hb + (size_t)wid * DIM + lane * 8);
        acc[0] = bf_lo(u.x); acc[1] = bf_hi(u.x);
        acc[2] = bf_lo(u.y); acc[3] = bf_hi(u.y);
        acc[4] = bf_lo(u.z); acc[5] = bf_hi(u.z);
        acc[6] = bf_lo(u.w); acc[7] = bf_hi(u.w);
    }
    int j = 0;
    for (; j + 8 <= cn; j += 8) {
        uint4 u[8];
        #pragma unroll
        for (int k = 0; k < 8; ++k) {
            int s = __shfl(myslot, j + k, 64);
            u[k] = *(const uint4*)(hb + (size_t)s * DIM + lane * 8);
        }
        #pragma unroll
        for (int k = 0; k < 8; ++k) {
            acc[0] += bf_lo(u[k].x); acc[1] += bf_hi(u[k].x);
            acc[2] += bf_lo(u[k].y); acc[3] += bf_hi(u[k].y);
            acc[4] += bf_lo(u[k].z); acc[5] += bf_hi(u[k].z);
            acc[6] += bf_lo(u[k].w); acc[7] += bf_hi(u[k].w);
        }
    }
    for (; j < cn; ++j) {
        int s = __shfl(myslot, j, 64);
        uint4 u = *(const uint4*)(hb + (size_t)s * DIM + lane * 8);
        acc[0] += bf_lo(u.x); acc[1] += bf_hi(u.x);
        acc[2] += bf_lo(u.y); acc[3] += bf_hi(u.y);
        acc[4] += bf_lo(u.z); acc[5] += bf_hi(u.z);
        acc[6] += bf_lo(u.w); acc[7] += bf_hi(u.w);
    }
    float inv = 1.0f / (float)(cn + 1);
    union { ushort_t us[8]; uint4 v; } pk;
    #pragma unroll
    for (int k = 0; k < 8; ++k) pk.us[k] = f2bf(acc[k] * inv);
    *(uint4*)(hmb + (size_t)wid * DIM + lane * 8) = pk.v;

    // router reduce: tot[c] = sum over lanes of qs[c]  (f32, exact slots sum)
    #pragma unroll
    for (int c = 0; c < NCENT; ++c) {
        float v = qs[c];
        #pragma unroll
        for (int s = 32; s > 0; s >>= 1) v += __shfl_xor(v, s, 64);
        qs[c] = v;
    }
    if (lane == 0) {
        const float* qn = q + (size_t)wid * NCENT;     // self-loop q row
        int best = 0; float bv = qs[0] + qn[0];
        #pragma unroll
        for (int c = 1; c < NCENT; ++c) {
            float v = qs[c] + qn[c];
            if (v > bv) { bv = v; best = c; }          // strict > = first max
        }
        route[wid] = best;
    }
}

// --- counting sort, phase 1: per-block 8-bin histogram (LDS only) ------------

__global__ __launch_bounds__(256) void route_hist_kernel(const int* __restrict__ route,
                                                         int* __restrict__ bhist, int N) {
    __shared__ int lh[NCENT];
    int t = threadIdx.x;
    if (t < NCENT) lh[t] = 0;
    __syncthreads();
    for (int i = blockIdx.x * 256 + t; i < N; i += NB * 256)
        atomicAdd(&lh[route[i]], 1);
    __syncthreads();
    if (t < NCENT) bhist[blockIdx.x * NCENT + t] = lh[t];
}

// --- counting sort, phase 2: scan bins -> goff/tloff/bbase (one block) -------

__global__ __launch_bounds__(512) void scan_bins_kernel(const int* __restrict__ bhist,
                                                        int* __restrict__ bbase,
                                                        int* __restrict__ goff,
                                                        int* __restrict__ tloff) {
    __shared__ int s[NCENT][NB];
    __shared__ int go[NCENT + 1], tl[NCENT + 1];
    int t = threadIdx.x;            // 512 = NB*NCENT
    int b = t >> 3, c = t & 7;
    int v = bhist[b * NCENT + c];
    s[c][b] = v;
    __syncthreads();
    for (int st = 1; st < NB; st <<= 1) {   // inclusive scan over b, per c
        int a = (b >= st) ? s[c][b - st] : 0;
        __syncthreads();
        s[c][b] += a;
        __syncthreads();
    }
    if (t == 0) {
        int g = 0, tt = 0;
        for (int cc = 0; cc < NCENT; ++cc) {
            go[cc] = g; tl[cc] = tt;
            int gc = s[cc][NB - 1];
            g += gc; tt += (gc + TM - 1) / TM;
        }
        go[NCENT] = g; tl[NCENT] = tt;
    }
    __syncthreads();
    bbase[b * NCENT + c] = go[c] + s[c][b] - v;      // exclusive + group base
    if (t < NCENT + 1) { goff[t] = go[t]; tloff[t] = tl[t]; }
}

// --- counting sort, phase 3: scatter with LDS cursors ------------------------

__global__ __launch_bounds__(256) void group_scatter2_kernel(
        const int* __restrict__ route, const int* __restrict__ bbase,
        int* __restrict__ nlist, int N) {
    __shared__ int lcur[NCENT];
    int t = threadIdx.x;
    if (t < NCENT) lcur[t] = bbase[blockIdx.x * NCENT + t];
    __syncthreads();
    for (int i = blockIdx.x * 256 + t; i < N; i += NB * 256) {
        int p = atomicAdd(&lcur[route[i]], 1);       // LDS atomic — no hot L2 line
        nlist[p] = i;
    }
}

// --- grouped GEMM via bf16 MFMA: out[n,:] = hmb[n,:] @ wtb[route]^T ----------
// C/D frag: col = l&15, row = (l>>4)*4 + reg (m89/m91-verified layout).

__global__ __launch_bounds__(256) void gemm_mfma_kernel(
        const ushort_t* __restrict__ hmb, const int* __restrict__ nlist,
        const int* __restrict__ goff, const int* __restrict__ tloff,
        const ushort_t* __restrict__ wtb, float* __restrict__ out) {
    __shared__ ushort_t a_s[TM * KP2];      // 9216 B
    __shared__ ushort_t b_s[NCLS * KP2];    // 18432 B
    __shared__ int nl_s[TM];

    int b = blockIdx.x;
    if (b >= tloff[NCENT]) return;
    int c = 0;
    while (b >= tloff[c + 1]) ++c;
    int row0 = goff[c] + (b - tloff[c]) * TM;
    int mrows = goff[c + 1] - row0; if (mrows > TM) mrows = TM;

    int tid = threadIdx.x;
    int wv = tid >> 6;                      // wave: rows [wv*16, wv*16+16)
    int lane = tid & 63;

    if (tid < TM) nl_s[tid] = nlist[row0 + (tid < mrows ? tid : mrows - 1)];
    __syncthreads();

    f32x4 acc[8];
    #pragma unroll
    for (int t = 0; t < 8; ++t) acc[t] = (f32x4){0.f, 0.f, 0.f, 0.f};

    const ushort_t* wt_c = wtb + (size_t)c * NCLS * DIM;

    for (int k0 = 0; k0 < DIM; k0 += KC2) {
        #pragma unroll
        for (int r = 0; r < 2; ++r) {               // stage A: 64x64 bf16
            int idx = tid + 256 * r;                // 0..511
            int row = idx >> 3;
            int kq = (idx & 7) * 8;
            int nd = nl_s[row];
            uint4 v = *(const uint4*)(hmb + (size_t)nd * DIM + k0 + kq);
            *(uint4*)&a_s[row * KP2 + kq] = v;
        }
        #pragma unroll
        for (int r = 0; r < 4; ++r) {               // stage B: 128x64 bf16
            int idx = tid + 256 * r;                // 0..1023
            int row = idx >> 3;
            int kq = (idx & 7) * 8;
            uint4 v = *(const uint4*)(wt_c + (size_t)row * DIM + k0 + kq);
            *(uint4*)&b_s[row * KP2 + kq] = v;
        }
        __syncthreads();
        #pragma unroll
        for (int s = 0; s < 2; ++s) {               // two K=32 steps
            int kof = s * 32 + (lane >> 4) * 8;
            bf16x8 af = *(const bf16x8*)&a_s[(wv * 16 + (lane & 15)) * KP2 + kof];
            #pragma unroll
            for (int t = 0; t < 8; ++t) {
                bf16x8 bf = *(const bf16x8*)&b_s[(t * 16 + (lane & 15)) * KP2 + kof];
                acc[t] = __builtin_amdgcn_mfma_f32_16x16x32_bf16(af, bf, acc[t], 0, 0, 0);
            }
        }
        __syncthreads();
    }

    #pragma unroll
    for (int r4 = 0; r4 < 4; ++r4) {
        int row = wv * 16 + (lane >> 4) * 4 + r4;
        if (row < mrows) {
            int nd = nl_s[row];
            float* orow = out + (size_t)nd * NCLS + (lane & 15);
            #pragma unroll
            for (int t = 0; t < 8; ++t)
                orow[t * 16] = acc[t][r4];
        }
    }
}

// --- Fallback: fused slots-based per-node kernel (f32 end-to-end) ------------

__global__ __launch_bounds__(256) void node_kernel(const float* __restrict__ h,
                                                   const int* __restrict__ cnt,
                                                   const int* __restrict__ slots,
                                                   const float* __restrict__ Ws,
                                                   const float* __restrict__ Wt,
                                                   float* __restrict__ out) {
    int node = blockIdx.x;
    int t = threadIdx.x;
    __shared__ float hm[DIM];
    __shared__ float sc[NCENT];
    __shared__ int route_s;

    int d0 = t * 2;
    float2 acc = *(const float2*)(h + (size_t)node * DIM + d0);
    int cn = cnt[node]; if (cn > WSLOT) cn = WSLOT;
    const int* sl = slots + (size_t)node * WSLOT;
    for (int j = 0; j < cn; ++j) {
        float2 v = *(const float2*)(h + (size_t)sl[j] * DIM + d0);
        acc.x += v.x; acc.y += v.y;
    }
    float inv = 1.0f / (float)(cn + 1);
    hm[d0] = acc.x * inv; hm[d0 + 1] = acc.y * inv;
    __syncthreads();
    if (t < NCENT) {
        const float* w = Ws + t * DIM;
        float s = 0.f;
        for (int d = 0; d < DIM; d += 4) {
            float4 a = *(const float4*)(&hm[d]);
            float4 b = *(const float4*)(w + d);
            s += a.x * b.x + a.y * b.y + a.z * b.z + a.w * b.w;
        }
        sc[t] = s;
    }
    __syncthreads();
    if (t == 0) {
        int best = 0; float bv = sc[0];
        #pragma unroll
        for (int c = 1; c < NCENT; ++c)
            if (sc[c] > bv) { bv = sc[c]; best = c; }
        route_s = best;
    }
    __syncthreads();
    int route = route_s;
    if (t < NCLS) {
        const float* w = Wt + ((size_t)route * NCLS + t) * DIM;
        float s = 0.f;
        for (int d = 0; d < DIM; d += 4) {
            float4 a = *(const float4*)(&hm[d]);
            float4 b = *(const float4*)(w + d);
            s += a.x * b.x + a.y * b.y + a.z * b.z + a.w * b.w;
        }
        out[(size_t)node * NCLS + t] = s;
    }
}

// --- launch ------------------------------------------------------------------

extern "C" void kernel_launch(void* const* d_in, const int* in_sizes, int n_in,
                              void* d_out, int out_size, void* d_ws, size_t ws_size,
                              hipStream_t stream) {
    const float* h   = (const float*)d_in[0];
    const int*   ei  = (const int*)d_in[1];
    const float* Ws  = (const float*)d_in[2];
    const float* Wt  = (const float*)d_in[3];
    float*       out = (float*)d_out;

    int N = in_sizes[0] / DIM;
    int E = in_sizes[1] / 2;
    int wt_elems = in_sizes[3];              // 8*128*512
    const int* esrc = ei;
    const int* edst = ei + E;

    int* wsp    = (int*)d_ws;
    int* cnt    = wsp;                       // N
    int* route  = cnt + N;                   // N
    int* goff   = route + N;                 // 9
    int* tloff  = goff + NCENT + 1;          // 9
    int* bhist  = tloff + NCENT + 1;         // NB*8
    int* bbase  = bhist + NB * NCENT;        // NB*8
    int* nlist  = bbase + NB * NCENT;        // N
    int* slots  = nlist + N;                 // N*WSLOT
    size_t iw   = (size_t)(3 * N) + 2 * (NCENT + 1) + 2 * NB * NCENT
                + (size_t)N * WSLOT;
    size_t q_off  = ((iw * 4 + 255) & ~(size_t)255);
    float* q    = (float*)((char*)d_ws + q_off);               // N*8 f32
    size_t hb_off = ((q_off + (size_t)N * NCENT * 4 + 255) & ~(size_t)255);
    ushort_t* hb = (ushort_t*)((char*)d_ws + hb_off);          // N*512 bf16
    size_t hmb_off = ((hb_off + (size_t)N * DIM * 2 + 255) & ~(size_t)255);
    ushort_t* hmb = (ushort_t*)((char*)d_ws + hmb_off);        // N*512 bf16
    size_t wtb_off = ((hmb_off + (size_t)N * DIM * 2 + 255) & ~(size_t)255);
    ushort_t* wtb = (ushort_t*)((char*)d_ws + wtb_off);        // 8*128*512 bf16
    size_t need = wtb_off + (size_t)wt_elems * 2;

    hipMemsetAsync(cnt, 0, (size_t)N * sizeof(int), stream);

    if (ws_size >= need) {
        int nprep = (N + 3) / 4;
        int total8 = wt_elems / 8;
        int nwt = (total8 + 255) / 256;
        prep_kernel<<<nprep + nwt, 256, 0, stream>>>(h, Ws, Wt, hb, q, wtb,
                                                     N, nprep, total8);
        scatter_pad_kernel<<<(E + 255) / 256, 256, 0, stream>>>(esrc, edst, cnt, slots, E);
        gather_route_kernel<<<(N + 3) / 4, 256, 0, stream>>>(hb, cnt, slots, q,
                                                             hmb, route, N);
        route_hist_kernel<<<NB, 256, 0, stream>>>(route, bhist, N);
        scan_bins_kernel<<<1, 512, 0, stream>>>(bhist, bbase, goff, tloff);
        group_scatter2_kernel<<<NB, 256, 0, stream>>>(route, bbase, nlist, N);
        int maxtiles = N / TM + NCENT + 1;
        gemm_mfma_kernel<<<maxtiles, 256, 0, stream>>>(hmb, nlist, goff, tloff, wtb, out);
    } else {
        scatter_pad_kernel<<<(E + 255) / 256, 256, 0, stream>>>(esrc, edst, cnt, slots, E);
        node_kernel<<<N, 256, 0, stream>>>(h, cnt, slots, Ws, Wt, out);
    }
}